// Round 4
// baseline (306.681 us; speedup 1.0000x reference)
//
#include <hip/hip_runtime.h>
#include <cstdint>
#include <cstddef>

#define B_    32
#define P_    16384
#define C_    80
#define NOBJ_ 50
#define THRESH_ 0.5f

static constexpr size_t OFF_ACC   = 0;
static constexpr size_t OFF_NNEG  = 512;
static constexpr size_t OFF_BP    = 1024;
static constexpr size_t OFF_BTOVL = 8192;
static constexpr size_t SZ_BP32   = (size_t)B_ * P_ * 4;
static constexpr size_t OFF_BTIDX = OFF_BTOVL + SZ_BP32;
static constexpr size_t OFF_MINEC = OFF_BTIDX + SZ_BP32;
static constexpr size_t OFF_MINEO = OFF_MINEC + SZ_BP32;
static constexpr size_t OFF_W     = OFF_MINEO + SZ_BP32;
static constexpr size_t OFF_POS   = OFF_W + SZ_BP32;

__device__ __forceinline__ unsigned fkey(float f) {
    unsigned u = __float_as_uint(f);
    return (u & 0x80000000u) ? ~u : (u | 0x80000000u);
}

// Wave-aggregated histogram add: lanes with equal `bin` merge into one atomic.
__device__ __forceinline__ void wave_hist_add(unsigned bin, unsigned* hist) {
    int lane = threadIdx.x & 63;
    unsigned long long active = __ballot(1);
    while (true) {
        int leader = __ffsll((long long)active) - 1;
        unsigned lbin = __shfl(bin, leader);
        unsigned long long same = __ballot(bin == lbin);
        if (bin == lbin) {
            if (lane == leader) atomicAdd(&hist[lbin], (unsigned)__popcll(same));
            break;
        }
        active &= ~same;
    }
}

__device__ double block_reduce_d(double v, double* sh, int nthreads) {
    int tid = threadIdx.x;
    sh[tid] = v; __syncthreads();
    for (int s = nthreads >> 1; s > 0; s >>= 1) {
        if (tid < s) sh[tid] += sh[tid + s];
        __syncthreads();
    }
    double r = sh[0]; __syncthreads();
    return r;
}

// Per-prior best truth (argmax over axis=0, first-index tie-break)
__global__ __launch_bounds__(256) void k_match_prior(
    const float* __restrict__ priors, const float* __restrict__ targets,
    float* __restrict__ btovl, int* __restrict__ btidx)
{
    int b = blockIdx.y;
    int p = blockIdx.x * 256 + threadIdx.x;
    __shared__ float tg[NOBJ_ * 6];
    __shared__ float areaA[NOBJ_];
    for (int i = threadIdx.x; i < NOBJ_ * 6; i += 256) tg[i] = targets[(size_t)b * NOBJ_ * 6 + i];
    __syncthreads();
    if (threadIdx.x < NOBJ_) {
        int t = threadIdx.x;
        areaA[t] = (tg[t*6+2] - tg[t*6+0]) * (tg[t*6+3] - tg[t*6+1]);
    }
    __syncthreads();
    float cx = priors[p*4], cy = priors[p*4+1], pw = priors[p*4+2], ph = priors[p*4+3];
    float bx1 = cx - pw*0.5f, by1 = cy - ph*0.5f, bx2 = cx + pw*0.5f, by2 = cy + ph*0.5f;
    float areaB = (bx2 - bx1) * (by2 - by1);
    float best = -1.0f; int bi = 0;
    for (int t = 0; t < NOBJ_; ++t) {
        float lx = fmaxf(tg[t*6+0], bx1), ly = fmaxf(tg[t*6+1], by1);
        float rx = fminf(tg[t*6+2], bx2), ry = fminf(tg[t*6+3], by2);
        float iw = fmaxf(rx - lx, 0.f), ih = fmaxf(ry - ly, 0.f);
        float inter = iw * ih;
        float iou = inter / (areaA[t] + areaB - inter);
        if (iou > best) { best = iou; bi = t; }
    }
    size_t ip = (size_t)b * P_ + p;
    btovl[ip] = best; btidx[ip] = bi;
}

// Per-truth best prior (argmax over axis=1, first-index tie-break)
__global__ __launch_bounds__(256) void k_best_prior(
    const float* __restrict__ priors, const float* __restrict__ targets,
    int* __restrict__ bp)
{
    int t = blockIdx.x, b = blockIdx.y, tid = threadIdx.x;
    const float* tr = targets + (size_t)(b * NOBJ_ + t) * 6;
    float x1 = tr[0], y1 = tr[1], x2 = tr[2], y2 = tr[3];
    float areaA = (x2 - x1) * (y2 - y1);
    float best = -1.f; int bi = 0;
    for (int p = tid; p < P_; p += 256) {
        float cx = priors[p*4], cy = priors[p*4+1], pw = priors[p*4+2], ph = priors[p*4+3];
        float bx1 = cx - pw*0.5f, by1 = cy - ph*0.5f, bx2 = cx + pw*0.5f, by2 = cy + ph*0.5f;
        float areaB = (bx2 - bx1) * (by2 - by1);
        float lx = fmaxf(x1, bx1), ly = fmaxf(y1, by1);
        float rx = fminf(x2, bx2), ry = fminf(y2, by2);
        float iw = fmaxf(rx - lx, 0.f), ih = fmaxf(ry - ly, 0.f);
        float inter = iw * ih;
        float iou = inter / (areaA + areaB - inter);
        if (iou > best) { best = iou; bi = p; }
    }
    __shared__ float sv[256];
    __shared__ int   si[256];
    sv[tid] = best; si[tid] = bi; __syncthreads();
    for (int s = 128; s > 0; s >>= 1) {
        if (tid < s) {
            if (sv[tid+s] > sv[tid] || (sv[tid+s] == sv[tid] && si[tid+s] < si[tid])) {
                sv[tid] = sv[tid+s]; si[tid] = si[tid+s];
            }
        }
        __syncthreads();
    }
    if (tid == 0) bp[b * NOBJ_ + t] = si[0];
}

// Parallel last-wins scatter: one block per batch; duplicate-resolution
// computed in LDS (lane i writes only if no later j has the same prior).
__global__ void k_scatter(const int* __restrict__ bp,
                          float* __restrict__ btovl, int* __restrict__ btidx)
{
    int b = blockIdx.x;
    int i = threadIdx.x;
    __shared__ int bpl[NOBJ_];
    if (i < NOBJ_) bpl[i] = bp[b * NOBJ_ + i];
    __syncthreads();
    if (i < NOBJ_) {
        int p = bpl[i];
        bool last = true;
        for (int j = i + 1; j < NOBJ_; ++j) if (bpl[j] == p) { last = false; break; }
        if (last) {
            btovl[(size_t)b * P_ + p] = 2.0f;
            btidx[(size_t)b * P_ + p] = i;
        }
    }
}

// Main pass. Phase A: wave-per-row coalesced conf logsumexp (64 rows/wave,
// butterfly shfl reductions, per-row lse parked in lane i's register).
// Phase B: lane-per-row for everything else (all accesses coalesced).
__global__ __launch_bounds__(256) void k_main(
    const float* __restrict__ loc, const float* __restrict__ conf,
    const float* __restrict__ obj, const float* __restrict__ priors,
    const float* __restrict__ targets,
    const float* __restrict__ btovl, const int* __restrict__ btidx,
    float* __restrict__ mine_c, float* __restrict__ mine_o,
    float* __restrict__ wArr, uint8_t* __restrict__ posArr,
    double* __restrict__ acc)
{
    int b = blockIdx.y;
    int wid = threadIdx.x >> 6;
    int lane = threadIdx.x & 63;
    int row0 = (blockIdx.x * 4 + wid) * 64;      // prior index base for this wave
    size_t base = (size_t)b * P_ + row0;         // global row base

    __shared__ float tg[NOBJ_ * 6];
    __shared__ double rd[256];
    for (int i = threadIdx.x; i < NOBJ_ * 6; i += 256) tg[i] = targets[(size_t)b * NOBJ_ * 6 + i];
    __syncthreads();

    // ---- Phase A: per-row logsumexp over conf (coalesced) ----
    float lsev = 0.f;
    const float* cb = conf + base * C_;
    #pragma unroll 2
    for (int i = 0; i < 64; ++i) {
        const float* crow = cb + (size_t)i * C_;
        float v0 = crow[lane];
        float v1 = (lane < 16) ? crow[64 + lane] : -INFINITY;
        float m = fmaxf(v0, v1);
        #pragma unroll
        for (int k = 32; k; k >>= 1) m = fmaxf(m, __shfl_xor(m, k));
        float s = expf(v0 - m) + ((lane < 16) ? expf(v1 - m) : 0.f);
        #pragma unroll
        for (int k = 32; k; k >>= 1) s += __shfl_xor(s, k);
        float l = m + logf(s);
        if (lane == i) lsev = l;
    }

    // ---- Phase B: lane-per-row ----
    int p = row0 + lane;
    size_t ip = base + lane;
    float ov = btovl[ip];
    int   ti = btidx[ip];
    float w  = tg[ti*6+5];
    bool pos = ov >= THRESH_;
    int  tgt = pos ? (int)tg[ti*6+4] : 0;

    float tx1 = tg[ti*6+0], ty1 = tg[ti*6+1], tx2 = tg[ti*6+2], ty2 = tg[ti*6+3];
    float cx = priors[p*4], cy = priors[p*4+1], pw = priors[p*4+2], ph = priors[p*4+3];
    float gx = ((tx1 + tx2) * 0.5f - cx) / (0.1f * pw);
    float gy = ((ty1 + ty2) * 0.5f - cy) / (0.1f * ph);
    float gw = logf((tx2 - tx1) / pw) * 5.0f;
    float gh = logf((ty2 - ty1) / ph) * 5.0f;

    const float* lr = loc + ip * 4;
    float sl1 = 0.f;
    {
        float g[4] = {gx, gy, gw, gh};
        #pragma unroll
        for (int k = 0; k < 4; ++k) {
            float d = lr[k] - g[k];
            float ad = fabsf(d);
            sl1 += (ad < 1.0f) ? 0.5f * d * d : ad - 0.5f;
        }
    }

    float o0 = obj[ip*2], o1 = obj[ip*2+1];
    float mo = fmaxf(o0, o1);
    float lae = mo + logf(expf(o0 - mo) + expf(o1 - mo));

    float ce_o = lae - (pos ? o1 : o0);
    float ce_c;
    if (tgt == 0) {
        ce_c = lae - o0;
    } else {
        float ctgt = conf[ip * C_ + (tgt - 1)];   // sparse (pos rows only)
        ce_c = lsev + lae - o1 - ctgt;
    }

    mine_c[ip] = pos ? 0.f : ce_c;
    mine_o[ip] = pos ? 0.f : ce_o;
    wArr[ip]   = w;
    posArr[ip] = pos ? 1 : 0;

    double pl = pos ? (double)(sl1 * w)  : 0.0;
    double pc = pos ? (double)(ce_c * w) : 0.0;
    double po = pos ? (double)(ce_o * w) : 0.0;
    double pn = pos ? (double)w          : 0.0;

    double r;
    r = block_reduce_d(pl, rd, 256); if (threadIdx.x == 0) atomicAdd(&acc[0], r);
    r = block_reduce_d(pc, rd, 256); if (threadIdx.x == 0) atomicAdd(&acc[1], r);
    r = block_reduce_d(po, rd, 256); if (threadIdx.x == 0) atomicAdd(&acc[2], r);
    r = block_reduce_d(pn, rd, 256); if (threadIdx.x == 0) atomicAdd(&acc[3 + b], r);
}

__global__ void k_numneg(const double* __restrict__ acc, int* __restrict__ num_neg)
{
    int b = threadIdx.x;
    if (b >= B_) return;
    int np = (int)acc[3 + b];
    int nn = 3 * np;
    num_neg[b] = nn < (P_ - 1) ? nn : (P_ - 1);
}

#define SEL_T 1024
#define TIE_CAP 1024

__device__ __forceinline__ void suffix_scan_2048(unsigned* c) {
    int tid = threadIdx.x;
    #pragma unroll
    for (int s = 1; s < 2048; s <<= 1) {
        unsigned a0 = (tid + s < 2048) ? c[tid + s] : 0u;
        unsigned a1 = (tid + 1024 + s < 2048) ? c[tid + 1024 + s] : 0u;
        __syncthreads();
        c[tid] += a0;
        c[tid + 1024] += a1;
        __syncthreads();
    }
}

__device__ __forceinline__ void find_bin(unsigned* c, int K, int* s_bin, int* s_pre) {
    int tid = threadIdx.x;
    #pragma unroll
    for (int i = 0; i < 2; ++i) {
        int bb = tid + i * 1024;
        unsigned cb = c[bb];
        unsigned cn = (bb == 2047) ? 0u : c[bb + 1];
        if (cb >= (unsigned)K && cn < (unsigned)K) { *s_bin = bb; *s_pre = (int)cn; }
    }
    __syncthreads();
}

// Exact top-K selection per (batch, branch) via 3-pass radix histogram.
__global__ __launch_bounds__(SEL_T) void k_select(
    const float* __restrict__ mine_c, const float* __restrict__ mine_o,
    const float* __restrict__ wArr, const uint8_t* __restrict__ posArr,
    const int* __restrict__ num_neg, double* __restrict__ acc)
{
    int b = blockIdx.x;
    int branch = blockIdx.y;
    int tid = threadIdx.x;
    int K = num_neg[b];
    if (K <= 0) return;

    const float* mrow = (branch ? mine_o : mine_c) + (size_t)b * P_;
    const float* wrow = wArr + (size_t)b * P_;
    const uint8_t* prow = posArr + (size_t)b * P_;

    __shared__ unsigned hist[2048];
    __shared__ int s_bin, s_pre;
    __shared__ int tcnt;
    __shared__ int tlist[TIE_CAP];
    __shared__ double rd[SEL_T];

    hist[tid] = 0; hist[tid + 1024] = 0;
    __syncthreads();
    for (int p = tid; p < P_; p += SEL_T) wave_hist_add(fkey(mrow[p]) >> 21, hist);
    __syncthreads();
    suffix_scan_2048(hist);
    find_bin(hist, K, &s_bin, &s_pre);
    int bin1 = s_bin, pre1 = s_pre;
    __syncthreads();

    hist[tid] = 0; hist[tid + 1024] = 0;
    __syncthreads();
    for (int p = tid; p < P_; p += SEL_T) {
        unsigned k = fkey(mrow[p]);
        if ((int)(k >> 21) == bin1) wave_hist_add((k >> 10) & 0x7FFu, hist);
    }
    __syncthreads();
    suffix_scan_2048(hist);
    find_bin(hist, K - pre1, &s_bin, &s_pre);
    int bin2 = s_bin, pre2 = s_pre;
    __syncthreads();

    hist[tid] = 0; hist[tid + 1024] = 0;
    __syncthreads();
    unsigned hi21 = ((unsigned)bin1 << 11) | (unsigned)bin2;
    for (int p = tid; p < P_; p += SEL_T) {
        unsigned k = fkey(mrow[p]);
        if ((k >> 10) == hi21) wave_hist_add(k & 0x3FFu, hist);
    }
    __syncthreads();
    suffix_scan_2048(hist);
    find_bin(hist, K - pre1 - pre2, &s_bin, &s_pre);
    int bin3 = s_bin, pre3 = s_pre;
    __syncthreads();

    unsigned T = (hi21 << 10) | (unsigned)bin3;
    int mslots = K - (pre1 + pre2 + pre3);

    if (tid == 0) tcnt = 0;
    __syncthreads();
    double sum = 0.0;
    for (int p = tid; p < P_; p += SEL_T) {
        float v = mrow[p];
        unsigned k = fkey(v);
        if (k > T) {
            if (!prow[p]) sum += (double)v * (double)wrow[p];
        } else if (k == T && !prow[p] && v != 0.0f) {
            int slot = atomicAdd(&tcnt, 1);
            if (slot < TIE_CAP) tlist[slot] = p;
        }
    }
    __syncthreads();
    int n = tcnt < TIE_CAP ? tcnt : TIE_CAP;
    if (tid < n) {
        int myp = tlist[tid];
        bool sel;
        if (n <= mslots) {
            sel = true;
        } else {
            int r = 0;
            for (int j = 0; j < n; ++j) if (tlist[j] < myp) ++r;
            sel = (r < mslots);
        }
        if (sel) sum += (double)mrow[myp] * (double)wrow[myp];
    }
    double r = block_reduce_d(sum, rd, SEL_T);
    if (tid == 0) atomicAdd(&acc[1 + branch], r);
}

__global__ void k_final(const double* __restrict__ acc, float* __restrict__ out)
{
    if (threadIdx.x == 0) {
        double N = 0.0;
        for (int b = 0; b < B_; ++b) N += acc[3 + b];
        out[0] = (float)(acc[0] / N);
        out[1] = (float)(acc[1] / N);
        out[2] = (float)(acc[2] / N);
    }
}

extern "C" void kernel_launch(void* const* d_in, const int* in_sizes, int n_in,
                              void* d_out, int out_size, void* d_ws, size_t ws_size,
                              hipStream_t stream)
{
    const float* loc     = (const float*)d_in[0];
    const float* conf    = (const float*)d_in[1];
    const float* obj     = (const float*)d_in[2];
    const float* priors  = (const float*)d_in[3];
    const float* targets = (const float*)d_in[4];
    float* out = (float*)d_out;

    char* ws = (char*)d_ws;
    double*  acc    = (double*)(ws + OFF_ACC);
    int*     nneg   = (int*)(ws + OFF_NNEG);
    int*     bp     = (int*)(ws + OFF_BP);
    float*   btovl  = (float*)(ws + OFF_BTOVL);
    int*     btidx  = (int*)(ws + OFF_BTIDX);
    float*   mine_c = (float*)(ws + OFF_MINEC);
    float*   mine_o = (float*)(ws + OFF_MINEO);
    float*   wArr   = (float*)(ws + OFF_W);
    uint8_t* posArr = (uint8_t*)(ws + OFF_POS);

    hipMemsetAsync(ws, 0, 512, stream);

    k_match_prior<<<dim3(P_/256, B_), 256, 0, stream>>>(priors, targets, btovl, btidx);
    k_best_prior <<<dim3(NOBJ_, B_), 256, 0, stream>>>(priors, targets, bp);
    k_scatter    <<<B_, 64, 0, stream>>>(bp, btovl, btidx);
    k_main       <<<dim3(P_/256, B_), 256, 0, stream>>>(loc, conf, obj, priors, targets,
                                                        btovl, btidx, mine_c, mine_o,
                                                        wArr, posArr, acc);
    k_numneg     <<<1, 64, 0, stream>>>(acc, nneg);
    k_select     <<<dim3(B_, 2), SEL_T, 0, stream>>>(mine_c, mine_o, wArr, posArr, nneg, acc);
    k_final      <<<1, 64, 0, stream>>>(acc, out);
}

// Round 5
// 268.053 us; speedup vs baseline: 1.1441x; 1.1441x over previous
//
#include <hip/hip_runtime.h>
#include <cstdint>
#include <cstddef>

#define B_    32
#define P_    16384
#define C_    80
#define NOBJ_ 50
#define THRESH_ 0.5f

static constexpr size_t OFF_ACC   = 0;
static constexpr size_t OFF_NNEG  = 512;
static constexpr size_t OFF_BP    = 1024;
static constexpr size_t OFF_BTOVL = 8192;
static constexpr size_t SZ_BP32   = (size_t)B_ * P_ * 4;
static constexpr size_t OFF_BTIDX = OFF_BTOVL + SZ_BP32;
static constexpr size_t OFF_MINEC = OFF_BTIDX + SZ_BP32;
static constexpr size_t OFF_MINEO = OFF_MINEC + SZ_BP32;
static constexpr size_t OFF_W     = OFF_MINEO + SZ_BP32;
static constexpr size_t OFF_POS   = OFF_W + SZ_BP32;

__device__ __forceinline__ unsigned fkey(float f) {
    unsigned u = __float_as_uint(f);
    return (u & 0x80000000u) ? ~u : (u | 0x80000000u);
}

// Wave-aggregated histogram add: lanes with equal `bin` merge into one atomic.
__device__ __forceinline__ void wave_hist_add(unsigned bin, unsigned* hist) {
    int lane = threadIdx.x & 63;
    unsigned long long active = __ballot(1);
    while (true) {
        int leader = __ffsll((long long)active) - 1;
        unsigned lbin = __shfl(bin, leader);
        unsigned long long same = __ballot(bin == lbin);
        if (bin == lbin) {
            if (lane == leader) atomicAdd(&hist[lbin], (unsigned)__popcll(same));
            break;
        }
        active &= ~same;
    }
}

__device__ double block_reduce_d(double v, double* sh, int nthreads) {
    int tid = threadIdx.x;
    sh[tid] = v; __syncthreads();
    for (int s = nthreads >> 1; s > 0; s >>= 1) {
        if (tid < s) sh[tid] += sh[tid + s];
        __syncthreads();
    }
    double r = sh[0]; __syncthreads();
    return r;
}

// Per-prior best truth (argmax over axis=0, first-index tie-break)
__global__ __launch_bounds__(256) void k_match_prior(
    const float* __restrict__ priors, const float* __restrict__ targets,
    float* __restrict__ btovl, int* __restrict__ btidx)
{
    int b = blockIdx.y;
    int p = blockIdx.x * 256 + threadIdx.x;
    __shared__ float tg[NOBJ_ * 6];
    __shared__ float areaA[NOBJ_];
    for (int i = threadIdx.x; i < NOBJ_ * 6; i += 256) tg[i] = targets[(size_t)b * NOBJ_ * 6 + i];
    __syncthreads();
    if (threadIdx.x < NOBJ_) {
        int t = threadIdx.x;
        areaA[t] = (tg[t*6+2] - tg[t*6+0]) * (tg[t*6+3] - tg[t*6+1]);
    }
    __syncthreads();
    float cx = priors[p*4], cy = priors[p*4+1], pw = priors[p*4+2], ph = priors[p*4+3];
    float bx1 = cx - pw*0.5f, by1 = cy - ph*0.5f, bx2 = cx + pw*0.5f, by2 = cy + ph*0.5f;
    float areaB = (bx2 - bx1) * (by2 - by1);
    float best = -1.0f; int bi = 0;
    for (int t = 0; t < NOBJ_; ++t) {
        float lx = fmaxf(tg[t*6+0], bx1), ly = fmaxf(tg[t*6+1], by1);
        float rx = fminf(tg[t*6+2], bx2), ry = fminf(tg[t*6+3], by2);
        float iw = fmaxf(rx - lx, 0.f), ih = fmaxf(ry - ly, 0.f);
        float inter = iw * ih;
        float iou = inter / (areaA[t] + areaB - inter);
        if (iou > best) { best = iou; bi = t; }
    }
    size_t ip = (size_t)b * P_ + p;
    btovl[ip] = best; btidx[ip] = bi;
}

// Per-truth best prior (argmax over axis=1, first-index tie-break)
__global__ __launch_bounds__(256) void k_best_prior(
    const float* __restrict__ priors, const float* __restrict__ targets,
    int* __restrict__ bp)
{
    int t = blockIdx.x, b = blockIdx.y, tid = threadIdx.x;
    const float* tr = targets + (size_t)(b * NOBJ_ + t) * 6;
    float x1 = tr[0], y1 = tr[1], x2 = tr[2], y2 = tr[3];
    float areaA = (x2 - x1) * (y2 - y1);
    float best = -1.f; int bi = 0;
    for (int p = tid; p < P_; p += 256) {
        float cx = priors[p*4], cy = priors[p*4+1], pw = priors[p*4+2], ph = priors[p*4+3];
        float bx1 = cx - pw*0.5f, by1 = cy - ph*0.5f, bx2 = cx + pw*0.5f, by2 = cy + ph*0.5f;
        float areaB = (bx2 - bx1) * (by2 - by1);
        float lx = fmaxf(x1, bx1), ly = fmaxf(y1, by1);
        float rx = fminf(x2, bx2), ry = fminf(y2, by2);
        float iw = fmaxf(rx - lx, 0.f), ih = fmaxf(ry - ly, 0.f);
        float inter = iw * ih;
        float iou = inter / (areaA + areaB - inter);
        if (iou > best) { best = iou; bi = p; }
    }
    __shared__ float sv[256];
    __shared__ int   si[256];
    sv[tid] = best; si[tid] = bi; __syncthreads();
    for (int s = 128; s > 0; s >>= 1) {
        if (tid < s) {
            if (sv[tid+s] > sv[tid] || (sv[tid+s] == sv[tid] && si[tid+s] < si[tid])) {
                sv[tid] = sv[tid+s]; si[tid] = si[tid+s];
            }
        }
        __syncthreads();
    }
    if (tid == 0) bp[b * NOBJ_ + t] = si[0];
}

// Parallel last-wins scatter: one block per batch.
__global__ void k_scatter(const int* __restrict__ bp,
                          float* __restrict__ btovl, int* __restrict__ btidx)
{
    int b = blockIdx.x;
    int i = threadIdx.x;
    __shared__ int bpl[NOBJ_];
    if (i < NOBJ_) bpl[i] = bp[b * NOBJ_ + i];
    __syncthreads();
    if (i < NOBJ_) {
        int p = bpl[i];
        bool last = true;
        for (int j = i + 1; j < NOBJ_; ++j) if (bpl[j] == p) { last = false; break; }
        if (last) {
            btovl[(size_t)b * P_ + p] = 2.0f;
            btidx[(size_t)b * P_ + p] = i;
        }
    }
}

// Main pass. Phase A: 4-lanes-per-row conf logsumexp (each lane owns 20
// elements = 5 float4; 16 rows per wave -> 5KB slab, tight L1 reuse; merge
// with 2 shfl_xor steps; lse -> LDS). Phase B: lane-per-row, coalesced.
__global__ __launch_bounds__(256) void k_main(
    const float* __restrict__ loc, const float* __restrict__ conf,
    const float* __restrict__ obj, const float* __restrict__ priors,
    const float* __restrict__ targets,
    const float* __restrict__ btovl, const int* __restrict__ btidx,
    float* __restrict__ mine_c, float* __restrict__ mine_o,
    float* __restrict__ wArr, uint8_t* __restrict__ posArr,
    double* __restrict__ acc)
{
    int b = blockIdx.y;
    int row_base = blockIdx.x * 256;             // block's first prior
    size_t base = (size_t)b * P_ + row_base;

    __shared__ float tg[NOBJ_ * 6];
    __shared__ float lse_sh[256];
    __shared__ double rd[256];
    for (int i = threadIdx.x; i < NOBJ_ * 6; i += 256) tg[i] = targets[(size_t)b * NOBJ_ * 6 + i];
    __syncthreads();

    // ---- Phase A ----
    {
        int sub  = threadIdx.x & 3;              // 20-element segment
        int rloc = threadIdx.x >> 2;             // row within 64-row group
        #pragma unroll
        for (int g = 0; g < 4; ++g) {
            int row = g * 64 + rloc;
            const float* crow = conf + (base + row) * C_ + sub * 20;
            float m = -INFINITY, s = 0.f;
            #pragma unroll
            for (int k = 0; k < 5; ++k) {
                float4 v = *(const float4*)(crow + k * 4);
                float m4 = fmaxf(fmaxf(v.x, v.y), fmaxf(v.z, v.w));
                float nm = fmaxf(m, m4);
                s = s * expf(m - nm) + expf(v.x - nm) + expf(v.y - nm)
                  + expf(v.z - nm) + expf(v.w - nm);
                m = nm;
            }
            #pragma unroll
            for (int d = 1; d <= 2; d <<= 1) {
                float mo = __shfl_xor(m, d);
                float so = __shfl_xor(s, d);
                float nm = fmaxf(m, mo);
                s = s * expf(m - nm) + so * expf(mo - nm);
                m = nm;
            }
            if (sub == 0) lse_sh[row] = m + logf(s);
        }
    }
    __syncthreads();

    // ---- Phase B ----
    int p = row_base + threadIdx.x;
    size_t ip = base + threadIdx.x;
    float lsev = lse_sh[threadIdx.x];
    float ov = btovl[ip];
    int   ti = btidx[ip];
    float w  = tg[ti*6+5];
    bool pos = ov >= THRESH_;
    int  tgt = pos ? (int)tg[ti*6+4] : 0;

    float tx1 = tg[ti*6+0], ty1 = tg[ti*6+1], tx2 = tg[ti*6+2], ty2 = tg[ti*6+3];
    float cx = priors[p*4], cy = priors[p*4+1], pw = priors[p*4+2], ph = priors[p*4+3];
    float gx = ((tx1 + tx2) * 0.5f - cx) / (0.1f * pw);
    float gy = ((ty1 + ty2) * 0.5f - cy) / (0.1f * ph);
    float gw = logf((tx2 - tx1) / pw) * 5.0f;
    float gh = logf((ty2 - ty1) / ph) * 5.0f;

    const float* lr = loc + ip * 4;
    float sl1 = 0.f;
    {
        float g[4] = {gx, gy, gw, gh};
        #pragma unroll
        for (int k = 0; k < 4; ++k) {
            float d = lr[k] - g[k];
            float ad = fabsf(d);
            sl1 += (ad < 1.0f) ? 0.5f * d * d : ad - 0.5f;
        }
    }

    float o0 = obj[ip*2], o1 = obj[ip*2+1];
    float mo = fmaxf(o0, o1);
    float lae = mo + logf(expf(o0 - mo) + expf(o1 - mo));

    float ce_o = lae - (pos ? o1 : o0);
    float ce_c;
    if (tgt == 0) {
        ce_c = lae - o0;
    } else {
        float ctgt = conf[ip * C_ + (tgt - 1)];   // sparse (pos rows only)
        ce_c = lsev + lae - o1 - ctgt;
    }

    mine_c[ip] = pos ? 0.f : ce_c;
    mine_o[ip] = pos ? 0.f : ce_o;
    wArr[ip]   = w;
    posArr[ip] = pos ? 1 : 0;

    double pl = pos ? (double)(sl1 * w)  : 0.0;
    double pc = pos ? (double)(ce_c * w) : 0.0;
    double po = pos ? (double)(ce_o * w) : 0.0;
    double pn = pos ? (double)w          : 0.0;

    double r;
    r = block_reduce_d(pl, rd, 256); if (threadIdx.x == 0) atomicAdd(&acc[0], r);
    r = block_reduce_d(pc, rd, 256); if (threadIdx.x == 0) atomicAdd(&acc[1], r);
    r = block_reduce_d(po, rd, 256); if (threadIdx.x == 0) atomicAdd(&acc[2], r);
    r = block_reduce_d(pn, rd, 256); if (threadIdx.x == 0) atomicAdd(&acc[3 + b], r);
}

__global__ void k_numneg(const double* __restrict__ acc, int* __restrict__ num_neg)
{
    int b = threadIdx.x;
    if (b >= B_) return;
    int np = (int)acc[3 + b];
    int nn = 3 * np;
    num_neg[b] = nn < (P_ - 1) ? nn : (P_ - 1);
}

#define SEL_T 1024
#define TIE_CAP 1024

__device__ __forceinline__ void suffix_scan_2048(unsigned* c) {
    int tid = threadIdx.x;
    #pragma unroll
    for (int s = 1; s < 2048; s <<= 1) {
        unsigned a0 = (tid + s < 2048) ? c[tid + s] : 0u;
        unsigned a1 = (tid + 1024 + s < 2048) ? c[tid + 1024 + s] : 0u;
        __syncthreads();
        c[tid] += a0;
        c[tid + 1024] += a1;
        __syncthreads();
    }
}

__device__ __forceinline__ void find_bin(unsigned* c, int K, int* s_bin, int* s_pre) {
    int tid = threadIdx.x;
    #pragma unroll
    for (int i = 0; i < 2; ++i) {
        int bb = tid + i * 1024;
        unsigned cb = c[bb];
        unsigned cn = (bb == 2047) ? 0u : c[bb + 1];
        if (cb >= (unsigned)K && cn < (unsigned)K) { *s_bin = bb; *s_pre = (int)cn; }
    }
    __syncthreads();
}

// Exact top-K selection per (batch, branch) via 3-pass radix histogram.
__global__ __launch_bounds__(SEL_T) void k_select(
    const float* __restrict__ mine_c, const float* __restrict__ mine_o,
    const float* __restrict__ wArr, const uint8_t* __restrict__ posArr,
    const int* __restrict__ num_neg, double* __restrict__ acc)
{
    int b = blockIdx.x;
    int branch = blockIdx.y;
    int tid = threadIdx.x;
    int K = num_neg[b];
    if (K <= 0) return;

    const float* mrow = (branch ? mine_o : mine_c) + (size_t)b * P_;
    const float* wrow = wArr + (size_t)b * P_;
    const uint8_t* prow = posArr + (size_t)b * P_;

    __shared__ unsigned hist[2048];
    __shared__ int s_bin, s_pre;
    __shared__ int tcnt;
    __shared__ int tlist[TIE_CAP];
    __shared__ double rd[SEL_T];

    hist[tid] = 0; hist[tid + 1024] = 0;
    __syncthreads();
    for (int p = tid; p < P_; p += SEL_T) wave_hist_add(fkey(mrow[p]) >> 21, hist);
    __syncthreads();
    suffix_scan_2048(hist);
    find_bin(hist, K, &s_bin, &s_pre);
    int bin1 = s_bin, pre1 = s_pre;
    __syncthreads();

    hist[tid] = 0; hist[tid + 1024] = 0;
    __syncthreads();
    for (int p = tid; p < P_; p += SEL_T) {
        unsigned k = fkey(mrow[p]);
        if ((int)(k >> 21) == bin1) wave_hist_add((k >> 10) & 0x7FFu, hist);
    }
    __syncthreads();
    suffix_scan_2048(hist);
    find_bin(hist, K - pre1, &s_bin, &s_pre);
    int bin2 = s_bin, pre2 = s_pre;
    __syncthreads();

    hist[tid] = 0; hist[tid + 1024] = 0;
    __syncthreads();
    unsigned hi21 = ((unsigned)bin1 << 11) | (unsigned)bin2;
    for (int p = tid; p < P_; p += SEL_T) {
        unsigned k = fkey(mrow[p]);
        if ((k >> 10) == hi21) wave_hist_add(k & 0x3FFu, hist);
    }
    __syncthreads();
    suffix_scan_2048(hist);
    find_bin(hist, K - pre1 - pre2, &s_bin, &s_pre);
    int bin3 = s_bin, pre3 = s_pre;
    __syncthreads();

    unsigned T = (hi21 << 10) | (unsigned)bin3;
    int mslots = K - (pre1 + pre2 + pre3);

    if (tid == 0) tcnt = 0;
    __syncthreads();
    double sum = 0.0;
    for (int p = tid; p < P_; p += SEL_T) {
        float v = mrow[p];
        unsigned k = fkey(v);
        if (k > T) {
            if (!prow[p]) sum += (double)v * (double)wrow[p];
        } else if (k == T && !prow[p] && v != 0.0f) {
            int slot = atomicAdd(&tcnt, 1);
            if (slot < TIE_CAP) tlist[slot] = p;
        }
    }
    __syncthreads();
    int n = tcnt < TIE_CAP ? tcnt : TIE_CAP;
    if (tid < n) {
        int myp = tlist[tid];
        bool sel;
        if (n <= mslots) {
            sel = true;
        } else {
            int r = 0;
            for (int j = 0; j < n; ++j) if (tlist[j] < myp) ++r;
            sel = (r < mslots);
        }
        if (sel) sum += (double)mrow[myp] * (double)wrow[myp];
    }
    double r = block_reduce_d(sum, rd, SEL_T);
    if (tid == 0) atomicAdd(&acc[1 + branch], r);
}

__global__ void k_final(const double* __restrict__ acc, float* __restrict__ out)
{
    if (threadIdx.x == 0) {
        double N = 0.0;
        for (int b = 0; b < B_; ++b) N += acc[3 + b];
        out[0] = (float)(acc[0] / N);
        out[1] = (float)(acc[1] / N);
        out[2] = (float)(acc[2] / N);
    }
}

extern "C" void kernel_launch(void* const* d_in, const int* in_sizes, int n_in,
                              void* d_out, int out_size, void* d_ws, size_t ws_size,
                              hipStream_t stream)
{
    const float* loc     = (const float*)d_in[0];
    const float* conf    = (const float*)d_in[1];
    const float* obj     = (const float*)d_in[2];
    const float* priors  = (const float*)d_in[3];
    const float* targets = (const float*)d_in[4];
    float* out = (float*)d_out;

    char* ws = (char*)d_ws;
    double*  acc    = (double*)(ws + OFF_ACC);
    int*     nneg   = (int*)(ws + OFF_NNEG);
    int*     bp     = (int*)(ws + OFF_BP);
    float*   btovl  = (float*)(ws + OFF_BTOVL);
    int*     btidx  = (int*)(ws + OFF_BTIDX);
    float*   mine_c = (float*)(ws + OFF_MINEC);
    float*   mine_o = (float*)(ws + OFF_MINEO);
    float*   wArr   = (float*)(ws + OFF_W);
    uint8_t* posArr = (uint8_t*)(ws + OFF_POS);

    hipMemsetAsync(ws, 0, 512, stream);

    k_match_prior<<<dim3(P_/256, B_), 256, 0, stream>>>(priors, targets, btovl, btidx);
    k_best_prior <<<dim3(NOBJ_, B_), 256, 0, stream>>>(priors, targets, bp);
    k_scatter    <<<B_, 64, 0, stream>>>(bp, btovl, btidx);
    k_main       <<<dim3(P_/256, B_), 256, 0, stream>>>(loc, conf, obj, priors, targets,
                                                        btovl, btidx, mine_c, mine_o,
                                                        wArr, posArr, acc);
    k_numneg     <<<1, 64, 0, stream>>>(acc, nneg);
    k_select     <<<dim3(B_, 2), SEL_T, 0, stream>>>(mine_c, mine_o, wArr, posArr, nneg, acc);
    k_final      <<<1, 64, 0, stream>>>(acc, out);
}

// Round 6
// 190.220 us; speedup vs baseline: 1.6122x; 1.4092x over previous
//
#include <hip/hip_runtime.h>
#include <cstdint>
#include <cstddef>

#define B_    32
#define P_    16384
#define C_    80
#define NOBJ_ 50
#define THRESH_ 0.5f

static constexpr size_t OFF_ACC   = 0;
static constexpr size_t OFF_NNEG  = 512;
static constexpr size_t OFF_BP    = 1024;
static constexpr size_t OFF_BTOVL = 8192;
static constexpr size_t SZ_BP32   = (size_t)B_ * P_ * 4;
static constexpr size_t OFF_BTIDX = OFF_BTOVL + SZ_BP32;
static constexpr size_t OFF_MINEC = OFF_BTIDX + SZ_BP32;
static constexpr size_t OFF_MINEO = OFF_MINEC + SZ_BP32;
static constexpr size_t OFF_W     = OFF_MINEO + SZ_BP32;
static constexpr size_t OFF_POS   = OFF_W + SZ_BP32;
static constexpr size_t OFF_PMAIN = OFF_POS + (size_t)B_ * P_;   // 2048*4 doubles
static constexpr size_t OFF_PSEL  = OFF_PMAIN + 2048 * 4 * 8;    // 64 doubles

__device__ __forceinline__ unsigned fkey(float f) {
    unsigned u = __float_as_uint(f);
    return (u & 0x80000000u) ? ~u : (u | 0x80000000u);
}

// Wave-aggregated histogram add: lanes with equal `bin` merge into one atomic.
__device__ __forceinline__ void wave_hist_add(unsigned bin, unsigned* hist) {
    int lane = threadIdx.x & 63;
    unsigned long long active = __ballot(1);
    while (true) {
        int leader = __ffsll((long long)active) - 1;
        unsigned lbin = __shfl(bin, leader);
        unsigned long long same = __ballot(bin == lbin);
        if (bin == lbin) {
            if (lane == leader) atomicAdd(&hist[lbin], (unsigned)__popcll(same));
            break;
        }
        active &= ~same;
    }
}

__device__ double block_reduce_d(double v, double* sh, int nthreads) {
    int tid = threadIdx.x;
    sh[tid] = v; __syncthreads();
    for (int s = nthreads >> 1; s > 0; s >>= 1) {
        if (tid < s) sh[tid] += sh[tid + s];
        __syncthreads();
    }
    double r = sh[0]; __syncthreads();
    return r;
}

// Per-prior best truth (argmax over axis=0, first-index tie-break)
__global__ __launch_bounds__(256) void k_match_prior(
    const float* __restrict__ priors, const float* __restrict__ targets,
    float* __restrict__ btovl, int* __restrict__ btidx)
{
    int b = blockIdx.y;
    int p = blockIdx.x * 256 + threadIdx.x;
    __shared__ float tg[NOBJ_ * 6];
    __shared__ float areaA[NOBJ_];
    for (int i = threadIdx.x; i < NOBJ_ * 6; i += 256) tg[i] = targets[(size_t)b * NOBJ_ * 6 + i];
    __syncthreads();
    if (threadIdx.x < NOBJ_) {
        int t = threadIdx.x;
        areaA[t] = (tg[t*6+2] - tg[t*6+0]) * (tg[t*6+3] - tg[t*6+1]);
    }
    __syncthreads();
    float cx = priors[p*4], cy = priors[p*4+1], pw = priors[p*4+2], ph = priors[p*4+3];
    float bx1 = cx - pw*0.5f, by1 = cy - ph*0.5f, bx2 = cx + pw*0.5f, by2 = cy + ph*0.5f;
    float areaB = (bx2 - bx1) * (by2 - by1);
    float best = -1.0f; int bi = 0;
    for (int t = 0; t < NOBJ_; ++t) {
        float lx = fmaxf(tg[t*6+0], bx1), ly = fmaxf(tg[t*6+1], by1);
        float rx = fminf(tg[t*6+2], bx2), ry = fminf(tg[t*6+3], by2);
        float iw = fmaxf(rx - lx, 0.f), ih = fmaxf(ry - ly, 0.f);
        float inter = iw * ih;
        float iou = inter / (areaA[t] + areaB - inter);
        if (iou > best) { best = iou; bi = t; }
    }
    size_t ip = (size_t)b * P_ + p;
    btovl[ip] = best; btidx[ip] = bi;
}

// Per-truth best prior (argmax over axis=1, first-index tie-break)
__global__ __launch_bounds__(256) void k_best_prior(
    const float* __restrict__ priors, const float* __restrict__ targets,
    int* __restrict__ bp)
{
    int t = blockIdx.x, b = blockIdx.y, tid = threadIdx.x;
    const float* tr = targets + (size_t)(b * NOBJ_ + t) * 6;
    float x1 = tr[0], y1 = tr[1], x2 = tr[2], y2 = tr[3];
    float areaA = (x2 - x1) * (y2 - y1);
    float best = -1.f; int bi = 0;
    for (int p = tid; p < P_; p += 256) {
        float cx = priors[p*4], cy = priors[p*4+1], pw = priors[p*4+2], ph = priors[p*4+3];
        float bx1 = cx - pw*0.5f, by1 = cy - ph*0.5f, bx2 = cx + pw*0.5f, by2 = cy + ph*0.5f;
        float areaB = (bx2 - bx1) * (by2 - by1);
        float lx = fmaxf(x1, bx1), ly = fmaxf(y1, by1);
        float rx = fminf(x2, bx2), ry = fminf(y2, by2);
        float iw = fmaxf(rx - lx, 0.f), ih = fmaxf(ry - ly, 0.f);
        float inter = iw * ih;
        float iou = inter / (areaA + areaB - inter);
        if (iou > best) { best = iou; bi = p; }
    }
    __shared__ float sv[256];
    __shared__ int   si[256];
    sv[tid] = best; si[tid] = bi; __syncthreads();
    for (int s = 128; s > 0; s >>= 1) {
        if (tid < s) {
            if (sv[tid+s] > sv[tid] || (sv[tid+s] == sv[tid] && si[tid+s] < si[tid])) {
                sv[tid] = sv[tid+s]; si[tid] = si[tid+s];
            }
        }
        __syncthreads();
    }
    if (tid == 0) bp[b * NOBJ_ + t] = si[0];
}

// Parallel last-wins scatter: one block per batch.
__global__ void k_scatter(const int* __restrict__ bp,
                          float* __restrict__ btovl, int* __restrict__ btidx)
{
    int b = blockIdx.x;
    int i = threadIdx.x;
    __shared__ int bpl[NOBJ_];
    if (i < NOBJ_) bpl[i] = bp[b * NOBJ_ + i];
    __syncthreads();
    if (i < NOBJ_) {
        int p = bpl[i];
        bool last = true;
        for (int j = i + 1; j < NOBJ_; ++j) if (bpl[j] == p) { last = false; break; }
        if (last) {
            btovl[(size_t)b * P_ + p] = 2.0f;
            btidx[(size_t)b * P_ + p] = i;
        }
    }
}

// Main pass. Phase A: 4-lanes-per-row conf logsumexp, two-pass (fmax tree,
// then __expf sum). Phase B: lane-per-row, coalesced. Block partials go to
// pmain[flat][4] via shfl wave-reduce (NO global atomics).
__global__ __launch_bounds__(256) void k_main(
    const float* __restrict__ loc, const float* __restrict__ conf,
    const float* __restrict__ obj, const float* __restrict__ priors,
    const float* __restrict__ targets,
    const float* __restrict__ btovl, const int* __restrict__ btidx,
    float* __restrict__ mine_c, float* __restrict__ mine_o,
    float* __restrict__ wArr, uint8_t* __restrict__ posArr,
    double* __restrict__ pmain)
{
    int b = blockIdx.y;
    int row_base = blockIdx.x * 256;
    size_t base = (size_t)b * P_ + row_base;

    __shared__ float tg[NOBJ_ * 6];
    __shared__ float lse_sh[256];
    __shared__ double wsum[4][4];
    for (int i = threadIdx.x; i < NOBJ_ * 6; i += 256) tg[i] = targets[(size_t)b * NOBJ_ * 6 + i];
    __syncthreads();

    // ---- Phase A ----
    {
        int sub  = threadIdx.x & 3;
        int rloc = threadIdx.x >> 2;
        #pragma unroll
        for (int g = 0; g < 4; ++g) {
            int row = g * 64 + rloc;
            const float4* cr = (const float4*)(conf + (base + row) * C_ + sub * 20);
            float4 a0 = cr[0], a1 = cr[1], a2 = cr[2], a3 = cr[3], a4 = cr[4];
            float m0 = fmaxf(fmaxf(a0.x, a0.y), fmaxf(a0.z, a0.w));
            float m1 = fmaxf(fmaxf(a1.x, a1.y), fmaxf(a1.z, a1.w));
            float m2 = fmaxf(fmaxf(a2.x, a2.y), fmaxf(a2.z, a2.w));
            float m3 = fmaxf(fmaxf(a3.x, a3.y), fmaxf(a3.z, a3.w));
            float m4 = fmaxf(fmaxf(a4.x, a4.y), fmaxf(a4.z, a4.w));
            float m  = fmaxf(fmaxf(fmaxf(m0, m1), fmaxf(m2, m3)), m4);
            float s  = (__expf(a0.x-m) + __expf(a0.y-m) + __expf(a0.z-m) + __expf(a0.w-m))
                     + (__expf(a1.x-m) + __expf(a1.y-m) + __expf(a1.z-m) + __expf(a1.w-m))
                     + (__expf(a2.x-m) + __expf(a2.y-m) + __expf(a2.z-m) + __expf(a2.w-m))
                     + (__expf(a3.x-m) + __expf(a3.y-m) + __expf(a3.z-m) + __expf(a3.w-m))
                     + (__expf(a4.x-m) + __expf(a4.y-m) + __expf(a4.z-m) + __expf(a4.w-m));
            #pragma unroll
            for (int d = 1; d <= 2; d <<= 1) {
                float mo = __shfl_xor(m, d);
                float so = __shfl_xor(s, d);
                float nm = fmaxf(m, mo);
                s = s * __expf(m - nm) + so * __expf(mo - nm);
                m = nm;
            }
            if (sub == 0) lse_sh[row] = m + __logf(s);
        }
    }
    __syncthreads();

    // ---- Phase B ----
    int p = row_base + threadIdx.x;
    size_t ip = base + threadIdx.x;
    float lsev = lse_sh[threadIdx.x];
    float ov = btovl[ip];
    int   ti = btidx[ip];
    float w  = tg[ti*6+5];
    bool pos = ov >= THRESH_;
    int  tgt = pos ? (int)tg[ti*6+4] : 0;

    float tx1 = tg[ti*6+0], ty1 = tg[ti*6+1], tx2 = tg[ti*6+2], ty2 = tg[ti*6+3];
    float cx = priors[p*4], cy = priors[p*4+1], pw = priors[p*4+2], ph = priors[p*4+3];
    float gx = ((tx1 + tx2) * 0.5f - cx) / (0.1f * pw);
    float gy = ((ty1 + ty2) * 0.5f - cy) / (0.1f * ph);
    float gw = __logf((tx2 - tx1) / pw) * 5.0f;
    float gh = __logf((ty2 - ty1) / ph) * 5.0f;

    const float* lr = loc + ip * 4;
    float sl1 = 0.f;
    {
        float g[4] = {gx, gy, gw, gh};
        #pragma unroll
        for (int k = 0; k < 4; ++k) {
            float d = lr[k] - g[k];
            float ad = fabsf(d);
            sl1 += (ad < 1.0f) ? 0.5f * d * d : ad - 0.5f;
        }
    }

    float o0 = obj[ip*2], o1 = obj[ip*2+1];
    float mo = fmaxf(o0, o1);
    float lae = mo + __logf(__expf(o0 - mo) + __expf(o1 - mo));

    float ce_o = lae - (pos ? o1 : o0);
    float ce_c;
    if (tgt == 0) {
        ce_c = lae - o0;
    } else {
        float ctgt = conf[ip * C_ + (tgt - 1)];   // sparse (pos rows only)
        ce_c = lsev + lae - o1 - ctgt;
    }

    mine_c[ip] = pos ? 0.f : ce_c;
    mine_o[ip] = pos ? 0.f : ce_o;
    wArr[ip]   = w;
    posArr[ip] = pos ? 1 : 0;

    double v0 = pos ? (double)(sl1 * w)  : 0.0;
    double v1 = pos ? (double)(ce_c * w) : 0.0;
    double v2 = pos ? (double)(ce_o * w) : 0.0;
    double v3 = pos ? (double)w          : 0.0;

    #pragma unroll
    for (int d = 32; d; d >>= 1) {
        v0 += __shfl_xor(v0, d);
        v1 += __shfl_xor(v1, d);
        v2 += __shfl_xor(v2, d);
        v3 += __shfl_xor(v3, d);
    }
    int wid = threadIdx.x >> 6, lane = threadIdx.x & 63;
    if (lane == 0) { wsum[wid][0] = v0; wsum[wid][1] = v1; wsum[wid][2] = v2; wsum[wid][3] = v3; }
    __syncthreads();
    if (threadIdx.x == 0) {
        double t0 = 0, t1 = 0, t2 = 0, t3 = 0;
        #pragma unroll
        for (int i = 0; i < 4; ++i) { t0 += wsum[i][0]; t1 += wsum[i][1]; t2 += wsum[i][2]; t3 += wsum[i][3]; }
        size_t flat = (size_t)b * gridDim.x + blockIdx.x;
        pmain[flat*4+0] = t0; pmain[flat*4+1] = t1; pmain[flat*4+2] = t2; pmain[flat*4+3] = t3;
    }
}

// Reduce pmain partials -> acc[0..2], acc[3+b], num_neg[b]. One block.
__global__ __launch_bounds__(1024) void k_reduce(
    const double* __restrict__ pmain, double* __restrict__ acc,
    int* __restrict__ num_neg)
{
    int tid = threadIdx.x;
    int lane = tid & 63, wid = tid >> 6;

    double s0 = 0, s1 = 0, s2 = 0;
    for (int i = tid; i < 2048; i += 1024) {
        const double* pr = pmain + (size_t)i * 4;
        s0 += pr[0]; s1 += pr[1]; s2 += pr[2];
    }

    // per-batch num_pos: batch b = tid>>5, lane-in-group j = tid&31
    {
        int b = tid >> 5, j = tid & 31;
        double pn = pmain[(size_t)(b * 64 + j) * 4 + 3]
                  + pmain[(size_t)(b * 64 + 32 + j) * 4 + 3];
        #pragma unroll
        for (int d = 16; d; d >>= 1) pn += __shfl_xor(pn, d);  // stays in 32-group
        if (j == 0) {
            acc[3 + b] = pn;
            int np = (int)pn;
            int nn = 3 * np;
            num_neg[b] = nn < (P_ - 1) ? nn : (P_ - 1);
        }
    }

    #pragma unroll
    for (int d = 32; d; d >>= 1) {
        s0 += __shfl_xor(s0, d); s1 += __shfl_xor(s1, d); s2 += __shfl_xor(s2, d);
    }
    __shared__ double sh3[16][3];
    if (lane == 0) { sh3[wid][0] = s0; sh3[wid][1] = s1; sh3[wid][2] = s2; }
    __syncthreads();
    if (tid == 0) {
        double a0 = 0, a1 = 0, a2 = 0;
        #pragma unroll
        for (int i = 0; i < 16; ++i) { a0 += sh3[i][0]; a1 += sh3[i][1]; a2 += sh3[i][2]; }
        acc[0] = a0; acc[1] = a1; acc[2] = a2;
    }
}

#define SEL_T 1024
#define TIE_CAP 1024

__device__ __forceinline__ void suffix_scan_2048(unsigned* c) {
    int tid = threadIdx.x;
    #pragma unroll
    for (int s = 1; s < 2048; s <<= 1) {
        unsigned a0 = (tid + s < 2048) ? c[tid + s] : 0u;
        unsigned a1 = (tid + 1024 + s < 2048) ? c[tid + 1024 + s] : 0u;
        __syncthreads();
        c[tid] += a0;
        c[tid + 1024] += a1;
        __syncthreads();
    }
}

__device__ __forceinline__ void find_bin(unsigned* c, int K, int* s_bin, int* s_pre) {
    int tid = threadIdx.x;
    #pragma unroll
    for (int i = 0; i < 2; ++i) {
        int bb = tid + i * 1024;
        unsigned cb = c[bb];
        unsigned cn = (bb == 2047) ? 0u : c[bb + 1];
        if (cb >= (unsigned)K && cn < (unsigned)K) { *s_bin = bb; *s_pre = (int)cn; }
    }
    __syncthreads();
}

// Exact top-K selection per (batch, branch) via 3-pass radix histogram.
// Writes per-block partial to psel (no global atomics).
__global__ __launch_bounds__(SEL_T) void k_select(
    const float* __restrict__ mine_c, const float* __restrict__ mine_o,
    const float* __restrict__ wArr, const uint8_t* __restrict__ posArr,
    const int* __restrict__ num_neg, double* __restrict__ psel)
{
    int b = blockIdx.x;
    int branch = blockIdx.y;
    int tid = threadIdx.x;
    int K = num_neg[b];
    if (tid == 0) psel[branch * B_ + b] = 0.0;
    if (K <= 0) return;

    const float* mrow = (branch ? mine_o : mine_c) + (size_t)b * P_;
    const float* wrow = wArr + (size_t)b * P_;
    const uint8_t* prow = posArr + (size_t)b * P_;

    __shared__ unsigned hist[2048];
    __shared__ int s_bin, s_pre;
    __shared__ int tcnt;
    __shared__ int tlist[TIE_CAP];
    __shared__ double rd[SEL_T];

    hist[tid] = 0; hist[tid + 1024] = 0;
    __syncthreads();
    for (int p = tid; p < P_; p += SEL_T) wave_hist_add(fkey(mrow[p]) >> 21, hist);
    __syncthreads();
    suffix_scan_2048(hist);
    find_bin(hist, K, &s_bin, &s_pre);
    int bin1 = s_bin, pre1 = s_pre;
    __syncthreads();

    hist[tid] = 0; hist[tid + 1024] = 0;
    __syncthreads();
    for (int p = tid; p < P_; p += SEL_T) {
        unsigned k = fkey(mrow[p]);
        if ((int)(k >> 21) == bin1) wave_hist_add((k >> 10) & 0x7FFu, hist);
    }
    __syncthreads();
    suffix_scan_2048(hist);
    find_bin(hist, K - pre1, &s_bin, &s_pre);
    int bin2 = s_bin, pre2 = s_pre;
    __syncthreads();

    hist[tid] = 0; hist[tid + 1024] = 0;
    __syncthreads();
    unsigned hi21 = ((unsigned)bin1 << 11) | (unsigned)bin2;
    for (int p = tid; p < P_; p += SEL_T) {
        unsigned k = fkey(mrow[p]);
        if ((k >> 10) == hi21) wave_hist_add(k & 0x3FFu, hist);
    }
    __syncthreads();
    suffix_scan_2048(hist);
    find_bin(hist, K - pre1 - pre2, &s_bin, &s_pre);
    int bin3 = s_bin, pre3 = s_pre;
    __syncthreads();

    unsigned T = (hi21 << 10) | (unsigned)bin3;
    int mslots = K - (pre1 + pre2 + pre3);

    if (tid == 0) tcnt = 0;
    __syncthreads();
    double sum = 0.0;
    for (int p = tid; p < P_; p += SEL_T) {
        float v = mrow[p];
        unsigned k = fkey(v);
        if (k > T) {
            if (!prow[p]) sum += (double)v * (double)wrow[p];
        } else if (k == T && !prow[p] && v != 0.0f) {
            int slot = atomicAdd(&tcnt, 1);
            if (slot < TIE_CAP) tlist[slot] = p;
        }
    }
    __syncthreads();
    int n = tcnt < TIE_CAP ? tcnt : TIE_CAP;
    if (tid < n) {
        int myp = tlist[tid];
        bool sel;
        if (n <= mslots) {
            sel = true;
        } else {
            int r = 0;
            for (int j = 0; j < n; ++j) if (tlist[j] < myp) ++r;
            sel = (r < mslots);
        }
        if (sel) sum += (double)mrow[myp] * (double)wrow[myp];
    }
    double r = block_reduce_d(sum, rd, SEL_T);
    if (tid == 0) psel[branch * B_ + b] = r;
}

__global__ void k_final(const double* __restrict__ acc,
                        const double* __restrict__ psel,
                        float* __restrict__ out)
{
    int lane = threadIdx.x;
    double v = psel[lane];   // [branch*32 + b], 64 entries
    #pragma unroll
    for (int d = 16; d; d >>= 1) v += __shfl_xor(v, d);  // sums within 32-groups
    double selc = __shfl(v, 0);
    double selo = __shfl(v, 32);
    if (lane == 0) {
        double N = 0.0;
        for (int b = 0; b < B_; ++b) N += acc[3 + b];
        out[0] = (float)(acc[0] / N);
        out[1] = (float)((acc[1] + selc) / N);
        out[2] = (float)((acc[2] + selo) / N);
    }
}

extern "C" void kernel_launch(void* const* d_in, const int* in_sizes, int n_in,
                              void* d_out, int out_size, void* d_ws, size_t ws_size,
                              hipStream_t stream)
{
    const float* loc     = (const float*)d_in[0];
    const float* conf    = (const float*)d_in[1];
    const float* obj     = (const float*)d_in[2];
    const float* priors  = (const float*)d_in[3];
    const float* targets = (const float*)d_in[4];
    float* out = (float*)d_out;

    char* ws = (char*)d_ws;
    double*  acc    = (double*)(ws + OFF_ACC);
    int*     nneg   = (int*)(ws + OFF_NNEG);
    int*     bp     = (int*)(ws + OFF_BP);
    float*   btovl  = (float*)(ws + OFF_BTOVL);
    int*     btidx  = (int*)(ws + OFF_BTIDX);
    float*   mine_c = (float*)(ws + OFF_MINEC);
    float*   mine_o = (float*)(ws + OFF_MINEO);
    float*   wArr   = (float*)(ws + OFF_W);
    uint8_t* posArr = (uint8_t*)(ws + OFF_POS);
    double*  pmain  = (double*)(ws + OFF_PMAIN);
    double*  psel   = (double*)(ws + OFF_PSEL);

    k_match_prior<<<dim3(P_/256, B_), 256, 0, stream>>>(priors, targets, btovl, btidx);
    k_best_prior <<<dim3(NOBJ_, B_), 256, 0, stream>>>(priors, targets, bp);
    k_scatter    <<<B_, 64, 0, stream>>>(bp, btovl, btidx);
    k_main       <<<dim3(P_/256, B_), 256, 0, stream>>>(loc, conf, obj, priors, targets,
                                                        btovl, btidx, mine_c, mine_o,
                                                        wArr, posArr, pmain);
    k_reduce     <<<1, 1024, 0, stream>>>(pmain, acc, nneg);
    k_select     <<<dim3(B_, 2), SEL_T, 0, stream>>>(mine_c, mine_o, wArr, posArr, nneg, psel);
    k_final      <<<1, 64, 0, stream>>>(acc, psel, out);
}

// Round 7
// 123.733 us; speedup vs baseline: 2.4786x; 1.5373x over previous
//
#include <hip/hip_runtime.h>
#include <cstdint>
#include <cstddef>

#define B_    32
#define P_    16384
#define C_    80
#define NOBJ_ 50
#define THRESH_ 0.5f

static constexpr size_t OFF_ACC   = 0;
static constexpr size_t OFF_NNEG  = 512;
static constexpr size_t OFF_BP    = 1024;
static constexpr size_t OFF_BTOVL = 8192;
static constexpr size_t SZ_BP32   = (size_t)B_ * P_ * 4;
static constexpr size_t OFF_BTIDX = OFF_BTOVL + SZ_BP32;
static constexpr size_t OFF_MINEC = OFF_BTIDX + SZ_BP32;
static constexpr size_t OFF_MINEO = OFF_MINEC + SZ_BP32;
static constexpr size_t OFF_W     = OFF_MINEO + SZ_BP32;
static constexpr size_t OFF_POS   = OFF_W + SZ_BP32;
static constexpr size_t OFF_PMAIN = OFF_POS + (size_t)B_ * P_;   // 2048*4 doubles
static constexpr size_t OFF_PSEL  = OFF_PMAIN + 2048 * 4 * 8;    // 64 doubles

__device__ __forceinline__ unsigned fkey(float f) {
    unsigned u = __float_as_uint(f);
    return (u & 0x80000000u) ? ~u : (u | 0x80000000u);
}

// Histogram add: 3 capped wave-aggregation peels (absorbs hot bins),
// then plain LDS atomicAdd fallback (diverse bins pipeline fine).
__device__ __forceinline__ void hist_add(unsigned bin, unsigned* hist) {
    int lane = threadIdx.x & 63;
    bool done = false;
    #pragma unroll
    for (int it = 0; it < 3; ++it) {
        unsigned long long active = __ballot(!done);
        if (!active) break;                       // wave-uniform
        int leader = __ffsll((long long)active) - 1;
        unsigned lbin = __shfl(bin, leader);
        unsigned long long same = __ballot(!done && bin == lbin);
        if (!done && bin == lbin) {
            if (lane == leader) atomicAdd(&hist[bin], (unsigned)__popcll(same));
            done = true;
        }
    }
    if (!done) atomicAdd(&hist[bin], 1u);
}

__device__ double block_reduce_d(double v, double* sh, int nthreads) {
    int tid = threadIdx.x;
    sh[tid] = v; __syncthreads();
    for (int s = nthreads >> 1; s > 0; s >>= 1) {
        if (tid < s) sh[tid] += sh[tid + s];
        __syncthreads();
    }
    double r = sh[0]; __syncthreads();
    return r;
}

// Per-prior best truth (argmax over axis=0, first-index tie-break)
__global__ __launch_bounds__(256) void k_match_prior(
    const float* __restrict__ priors, const float* __restrict__ targets,
    float* __restrict__ btovl, int* __restrict__ btidx)
{
    int b = blockIdx.y;
    int p = blockIdx.x * 256 + threadIdx.x;
    __shared__ float tg[NOBJ_ * 6];
    __shared__ float areaA[NOBJ_];
    for (int i = threadIdx.x; i < NOBJ_ * 6; i += 256) tg[i] = targets[(size_t)b * NOBJ_ * 6 + i];
    __syncthreads();
    if (threadIdx.x < NOBJ_) {
        int t = threadIdx.x;
        areaA[t] = (tg[t*6+2] - tg[t*6+0]) * (tg[t*6+3] - tg[t*6+1]);
    }
    __syncthreads();
    float4 pr = ((const float4*)priors)[p];
    float bx1 = pr.x - pr.z*0.5f, by1 = pr.y - pr.w*0.5f;
    float bx2 = pr.x + pr.z*0.5f, by2 = pr.y + pr.w*0.5f;
    float areaB = (bx2 - bx1) * (by2 - by1);
    float best = -1.0f; int bi = 0;
    for (int t = 0; t < NOBJ_; ++t) {
        float lx = fmaxf(tg[t*6+0], bx1), ly = fmaxf(tg[t*6+1], by1);
        float rx = fminf(tg[t*6+2], bx2), ry = fminf(tg[t*6+3], by2);
        float iw = fmaxf(rx - lx, 0.f), ih = fmaxf(ry - ly, 0.f);
        float inter = iw * ih;
        float iou = inter / (areaA[t] + areaB - inter);
        if (iou > best) { best = iou; bi = t; }
    }
    size_t ip = (size_t)b * P_ + p;
    btovl[ip] = best; btidx[ip] = bi;
}

// Per-truth best prior (argmax over axis=1, first-index tie-break)
__global__ __launch_bounds__(256) void k_best_prior(
    const float* __restrict__ priors, const float* __restrict__ targets,
    int* __restrict__ bp)
{
    int t = blockIdx.x, b = blockIdx.y, tid = threadIdx.x;
    const float* tr = targets + (size_t)(b * NOBJ_ + t) * 6;
    float x1 = tr[0], y1 = tr[1], x2 = tr[2], y2 = tr[3];
    float areaA = (x2 - x1) * (y2 - y1);
    float best = -1.f; int bi = 0;
    for (int p = tid; p < P_; p += 256) {
        float4 pr = ((const float4*)priors)[p];
        float bx1 = pr.x - pr.z*0.5f, by1 = pr.y - pr.w*0.5f;
        float bx2 = pr.x + pr.z*0.5f, by2 = pr.y + pr.w*0.5f;
        float areaB = (bx2 - bx1) * (by2 - by1);
        float lx = fmaxf(x1, bx1), ly = fmaxf(y1, by1);
        float rx = fminf(x2, bx2), ry = fminf(y2, by2);
        float iw = fmaxf(rx - lx, 0.f), ih = fmaxf(ry - ly, 0.f);
        float inter = iw * ih;
        float iou = inter / (areaA + areaB - inter);
        if (iou > best) { best = iou; bi = p; }
    }
    __shared__ float sv[256];
    __shared__ int   si[256];
    sv[tid] = best; si[tid] = bi; __syncthreads();
    for (int s = 128; s > 0; s >>= 1) {
        if (tid < s) {
            if (sv[tid+s] > sv[tid] || (sv[tid+s] == sv[tid] && si[tid+s] < si[tid])) {
                sv[tid] = sv[tid+s]; si[tid] = si[tid+s];
            }
        }
        __syncthreads();
    }
    if (tid == 0) bp[b * NOBJ_ + t] = si[0];
}

// Parallel last-wins scatter: one block per batch.
__global__ void k_scatter(const int* __restrict__ bp,
                          float* __restrict__ btovl, int* __restrict__ btidx)
{
    int b = blockIdx.x;
    int i = threadIdx.x;
    __shared__ int bpl[NOBJ_];
    if (i < NOBJ_) bpl[i] = bp[b * NOBJ_ + i];
    __syncthreads();
    if (i < NOBJ_) {
        int p = bpl[i];
        bool last = true;
        for (int j = i + 1; j < NOBJ_; ++j) if (bpl[j] == p) { last = false; break; }
        if (last) {
            btovl[(size_t)b * P_ + p] = 2.0f;
            btidx[(size_t)b * P_ + p] = i;
        }
    }
}

// Main pass. Phase A: 4-lanes-per-row conf logsumexp, two-pass.
// Phase B: lane-per-row, coalesced. Partials to pmain (no global atomics).
__global__ __launch_bounds__(256) void k_main(
    const float* __restrict__ loc, const float* __restrict__ conf,
    const float* __restrict__ obj, const float* __restrict__ priors,
    const float* __restrict__ targets,
    const float* __restrict__ btovl, const int* __restrict__ btidx,
    float* __restrict__ mine_c, float* __restrict__ mine_o,
    float* __restrict__ wArr, uint8_t* __restrict__ posArr,
    double* __restrict__ pmain)
{
    int b = blockIdx.y;
    int row_base = blockIdx.x * 256;
    size_t base = (size_t)b * P_ + row_base;

    __shared__ float tg[NOBJ_ * 6];
    __shared__ float lse_sh[256];
    __shared__ double wsum[4][4];
    for (int i = threadIdx.x; i < NOBJ_ * 6; i += 256) tg[i] = targets[(size_t)b * NOBJ_ * 6 + i];
    __syncthreads();

    // ---- Phase A ----
    {
        int sub  = threadIdx.x & 3;
        int rloc = threadIdx.x >> 2;
        #pragma unroll
        for (int g = 0; g < 4; ++g) {
            int row = g * 64 + rloc;
            const float4* cr = (const float4*)(conf + (base + row) * C_ + sub * 20);
            float4 a0 = cr[0], a1 = cr[1], a2 = cr[2], a3 = cr[3], a4 = cr[4];
            float m0 = fmaxf(fmaxf(a0.x, a0.y), fmaxf(a0.z, a0.w));
            float m1 = fmaxf(fmaxf(a1.x, a1.y), fmaxf(a1.z, a1.w));
            float m2 = fmaxf(fmaxf(a2.x, a2.y), fmaxf(a2.z, a2.w));
            float m3 = fmaxf(fmaxf(a3.x, a3.y), fmaxf(a3.z, a3.w));
            float m4 = fmaxf(fmaxf(a4.x, a4.y), fmaxf(a4.z, a4.w));
            float m  = fmaxf(fmaxf(fmaxf(m0, m1), fmaxf(m2, m3)), m4);
            float s  = (__expf(a0.x-m) + __expf(a0.y-m) + __expf(a0.z-m) + __expf(a0.w-m))
                     + (__expf(a1.x-m) + __expf(a1.y-m) + __expf(a1.z-m) + __expf(a1.w-m))
                     + (__expf(a2.x-m) + __expf(a2.y-m) + __expf(a2.z-m) + __expf(a2.w-m))
                     + (__expf(a3.x-m) + __expf(a3.y-m) + __expf(a3.z-m) + __expf(a3.w-m))
                     + (__expf(a4.x-m) + __expf(a4.y-m) + __expf(a4.z-m) + __expf(a4.w-m));
            #pragma unroll
            for (int d = 1; d <= 2; d <<= 1) {
                float mo = __shfl_xor(m, d);
                float so = __shfl_xor(s, d);
                float nm = fmaxf(m, mo);
                s = s * __expf(m - nm) + so * __expf(mo - nm);
                m = nm;
            }
            if (sub == 0) lse_sh[row] = m + __logf(s);
        }
    }
    __syncthreads();

    // ---- Phase B ----
    int p = row_base + threadIdx.x;
    size_t ip = base + threadIdx.x;
    float lsev = lse_sh[threadIdx.x];
    float ov = btovl[ip];
    int   ti = btidx[ip];
    float w  = tg[ti*6+5];
    bool pos = ov >= THRESH_;
    int  tgt = pos ? (int)tg[ti*6+4] : 0;

    float tx1 = tg[ti*6+0], ty1 = tg[ti*6+1], tx2 = tg[ti*6+2], ty2 = tg[ti*6+3];
    float4 prv = ((const float4*)priors)[p];
    float gx = ((tx1 + tx2) * 0.5f - prv.x) / (0.1f * prv.z);
    float gy = ((ty1 + ty2) * 0.5f - prv.y) / (0.1f * prv.w);
    float gw = __logf((tx2 - tx1) / prv.z) * 5.0f;
    float gh = __logf((ty2 - ty1) / prv.w) * 5.0f;

    float4 l4 = ((const float4*)loc)[ip];
    float sl1 = 0.f;
    {
        float lrk[4] = {l4.x, l4.y, l4.z, l4.w};
        float g[4] = {gx, gy, gw, gh};
        #pragma unroll
        for (int k = 0; k < 4; ++k) {
            float d = lrk[k] - g[k];
            float ad = fabsf(d);
            sl1 += (ad < 1.0f) ? 0.5f * d * d : ad - 0.5f;
        }
    }

    float2 ob = ((const float2*)obj)[ip];
    float o0 = ob.x, o1 = ob.y;
    float mo = fmaxf(o0, o1);
    float lae = mo + __logf(__expf(o0 - mo) + __expf(o1 - mo));

    float ce_o = lae - (pos ? o1 : o0);
    float ce_c;
    if (tgt == 0) {
        ce_c = lae - o0;
    } else {
        float ctgt = conf[ip * C_ + (tgt - 1)];   // sparse (pos rows only)
        ce_c = lsev + lae - o1 - ctgt;
    }

    mine_c[ip] = pos ? 0.f : ce_c;
    mine_o[ip] = pos ? 0.f : ce_o;
    wArr[ip]   = w;
    posArr[ip] = pos ? 1 : 0;

    double v0 = pos ? (double)(sl1 * w)  : 0.0;
    double v1 = pos ? (double)(ce_c * w) : 0.0;
    double v2 = pos ? (double)(ce_o * w) : 0.0;
    double v3 = pos ? (double)w          : 0.0;

    #pragma unroll
    for (int d = 32; d; d >>= 1) {
        v0 += __shfl_xor(v0, d);
        v1 += __shfl_xor(v1, d);
        v2 += __shfl_xor(v2, d);
        v3 += __shfl_xor(v3, d);
    }
    int wid = threadIdx.x >> 6, lane = threadIdx.x & 63;
    if (lane == 0) { wsum[wid][0] = v0; wsum[wid][1] = v1; wsum[wid][2] = v2; wsum[wid][3] = v3; }
    __syncthreads();
    if (threadIdx.x == 0) {
        double t0 = 0, t1 = 0, t2 = 0, t3 = 0;
        #pragma unroll
        for (int i = 0; i < 4; ++i) { t0 += wsum[i][0]; t1 += wsum[i][1]; t2 += wsum[i][2]; t3 += wsum[i][3]; }
        size_t flat = (size_t)b * gridDim.x + blockIdx.x;
        pmain[flat*4+0] = t0; pmain[flat*4+1] = t1; pmain[flat*4+2] = t2; pmain[flat*4+3] = t3;
    }
}

// Reduce pmain partials -> acc[0..2], acc[3+b], num_neg[b]. One block.
__global__ __launch_bounds__(1024) void k_reduce(
    const double* __restrict__ pmain, double* __restrict__ acc,
    int* __restrict__ num_neg)
{
    int tid = threadIdx.x;
    int lane = tid & 63, wid = tid >> 6;

    double s0 = 0, s1 = 0, s2 = 0;
    for (int i = tid; i < 2048; i += 1024) {
        const double* pr = pmain + (size_t)i * 4;
        s0 += pr[0]; s1 += pr[1]; s2 += pr[2];
    }

    {
        int b = tid >> 5, j = tid & 31;
        double pn = pmain[(size_t)(b * 64 + j) * 4 + 3]
                  + pmain[(size_t)(b * 64 + 32 + j) * 4 + 3];
        #pragma unroll
        for (int d = 16; d; d >>= 1) pn += __shfl_xor(pn, d);
        if (j == 0) {
            acc[3 + b] = pn;
            int np = (int)pn;
            int nn = 3 * np;
            num_neg[b] = nn < (P_ - 1) ? nn : (P_ - 1);
        }
    }

    #pragma unroll
    for (int d = 32; d; d >>= 1) {
        s0 += __shfl_xor(s0, d); s1 += __shfl_xor(s1, d); s2 += __shfl_xor(s2, d);
    }
    __shared__ double sh3[16][3];
    if (lane == 0) { sh3[wid][0] = s0; sh3[wid][1] = s1; sh3[wid][2] = s2; }
    __syncthreads();
    if (tid == 0) {
        double a0 = 0, a1 = 0, a2 = 0;
        #pragma unroll
        for (int i = 0; i < 16; ++i) { a0 += sh3[i][0]; a1 += sh3[i][1]; a2 += sh3[i][2]; }
        acc[0] = a0; acc[1] = a1; acc[2] = a2;
    }
}

#define SEL_T 1024
#define TIE_CAP 1024

// Hierarchical suffix scan: per-wave shfl_down scan + 16 wave totals.
// 3 barriers total (vs 22 for Hillis-Steele).
__device__ __forceinline__ void suffix_scan_2048(unsigned* c, unsigned* wtot) {
    int tid = threadIdx.x;
    int lane = tid & 63, wid = tid >> 6;
    unsigned lo = c[2*tid], hi = c[2*tid+1];
    unsigned s_hi = hi;
    unsigned s_lo = lo + hi;
    unsigned tot = s_lo;
    unsigned run = tot;
    #pragma unroll
    for (int d = 1; d < 64; d <<= 1) {
        unsigned o = __shfl_down(run, d);
        if (lane + d < 64) run += o;
    }
    if (lane == 0) wtot[wid] = run;
    __syncthreads();
    unsigned woff = 0;
    #pragma unroll
    for (int w = 0; w < 16; ++w) if (w > wid) woff += wtot[w];
    unsigned base = woff + (run - tot);
    __syncthreads();
    c[2*tid]   = base + s_lo;
    c[2*tid+1] = base + s_hi;
    __syncthreads();
}

__device__ __forceinline__ void find_bin(unsigned* c, int K, int* s_bin, int* s_pre) {
    int tid = threadIdx.x;
    #pragma unroll
    for (int i = 0; i < 2; ++i) {
        int bb = tid + i * 1024;
        unsigned cb = c[bb];
        unsigned cn = (bb == 2047) ? 0u : c[bb + 1];
        if (cb >= (unsigned)K && cn < (unsigned)K) { *s_bin = bb; *s_pre = (int)cn; }
    }
    __syncthreads();
}

// Exact top-K selection per (batch, branch) via 3-pass radix histogram.
__global__ __launch_bounds__(SEL_T) void k_select(
    const float* __restrict__ mine_c, const float* __restrict__ mine_o,
    const float* __restrict__ wArr, const uint8_t* __restrict__ posArr,
    const int* __restrict__ num_neg, double* __restrict__ psel)
{
    int b = blockIdx.x;
    int branch = blockIdx.y;
    int tid = threadIdx.x;
    int K = num_neg[b];
    if (tid == 0) psel[branch * B_ + b] = 0.0;
    if (K <= 0) return;

    const float* mrow = (branch ? mine_o : mine_c) + (size_t)b * P_;
    const float4* m4 = (const float4*)mrow;
    const float4* w4 = (const float4*)(wArr + (size_t)b * P_);
    const uchar4* p4 = (const uchar4*)(posArr + (size_t)b * P_);

    __shared__ unsigned hist[2048];
    __shared__ unsigned wtot[16];
    __shared__ int s_bin, s_pre;
    __shared__ int tcnt;
    __shared__ int tlist[TIE_CAP];
    __shared__ double rd[SEL_T];

    // ---- pass 1: bits [31:21] ----
    hist[tid] = 0; hist[tid + 1024] = 0;
    __syncthreads();
    for (int i = tid; i < P_/4; i += SEL_T) {
        float4 v = m4[i];
        hist_add(fkey(v.x) >> 21, hist);
        hist_add(fkey(v.y) >> 21, hist);
        hist_add(fkey(v.z) >> 21, hist);
        hist_add(fkey(v.w) >> 21, hist);
    }
    __syncthreads();
    suffix_scan_2048(hist, wtot);
    find_bin(hist, K, &s_bin, &s_pre);
    int bin1 = s_bin, pre1 = s_pre;
    __syncthreads();

    // ---- pass 2: bits [20:10] among elements with top bits == bin1 ----
    hist[tid] = 0; hist[tid + 1024] = 0;
    __syncthreads();
    for (int i = tid; i < P_/4; i += SEL_T) {
        float4 v = m4[i];
        unsigned k0 = fkey(v.x), k1 = fkey(v.y), k2 = fkey(v.z), k3 = fkey(v.w);
        if ((int)(k0 >> 21) == bin1) hist_add((k0 >> 10) & 0x7FFu, hist);
        if ((int)(k1 >> 21) == bin1) hist_add((k1 >> 10) & 0x7FFu, hist);
        if ((int)(k2 >> 21) == bin1) hist_add((k2 >> 10) & 0x7FFu, hist);
        if ((int)(k3 >> 21) == bin1) hist_add((k3 >> 10) & 0x7FFu, hist);
    }
    __syncthreads();
    suffix_scan_2048(hist, wtot);
    find_bin(hist, K - pre1, &s_bin, &s_pre);
    int bin2 = s_bin, pre2 = s_pre;
    __syncthreads();

    // ---- pass 3: bits [9:0] ----
    hist[tid] = 0; hist[tid + 1024] = 0;
    __syncthreads();
    unsigned hi21 = ((unsigned)bin1 << 11) | (unsigned)bin2;
    for (int i = tid; i < P_/4; i += SEL_T) {
        float4 v = m4[i];
        unsigned k0 = fkey(v.x), k1 = fkey(v.y), k2 = fkey(v.z), k3 = fkey(v.w);
        if ((k0 >> 10) == hi21) hist_add(k0 & 0x3FFu, hist);
        if ((k1 >> 10) == hi21) hist_add(k1 & 0x3FFu, hist);
        if ((k2 >> 10) == hi21) hist_add(k2 & 0x3FFu, hist);
        if ((k3 >> 10) == hi21) hist_add(k3 & 0x3FFu, hist);
    }
    __syncthreads();
    suffix_scan_2048(hist, wtot);
    find_bin(hist, K - pre1 - pre2, &s_bin, &s_pre);
    int bin3 = s_bin, pre3 = s_pre;
    __syncthreads();

    unsigned T = (hi21 << 10) | (unsigned)bin3;
    int mslots = K - (pre1 + pre2 + pre3);

    // ---- sum k > T; gather key==T ties ----
    if (tid == 0) tcnt = 0;
    __syncthreads();
    double sum = 0.0;
    for (int i = tid; i < P_/4; i += SEL_T) {
        float4 v = m4[i];
        float4 wv = w4[i];
        uchar4 pv = p4[i];
        float  vv[4] = {v.x, v.y, v.z, v.w};
        float  ww[4] = {wv.x, wv.y, wv.z, wv.w};
        unsigned char pp[4] = {pv.x, pv.y, pv.z, pv.w};
        #pragma unroll
        for (int j = 0; j < 4; ++j) {
            unsigned k = fkey(vv[j]);
            if (k > T) {
                if (!pp[j]) sum += (double)vv[j] * (double)ww[j];
            } else if (k == T && !pp[j] && vv[j] != 0.0f) {
                int slot = atomicAdd(&tcnt, 1);
                if (slot < TIE_CAP) tlist[slot] = i * 4 + j;
            }
        }
    }
    __syncthreads();
    int n = tcnt < TIE_CAP ? tcnt : TIE_CAP;
    if (tid < n) {
        int myp = tlist[tid];
        bool sel;
        if (n <= mslots) {
            sel = true;
        } else {
            int r = 0;
            for (int j = 0; j < n; ++j) if (tlist[j] < myp) ++r;
            sel = (r < mslots);
        }
        if (sel) sum += (double)mrow[myp] * (double)(wArr + (size_t)b * P_)[myp];
    }
    double r = block_reduce_d(sum, rd, SEL_T);
    if (tid == 0) psel[branch * B_ + b] = r;
}

__global__ void k_final(const double* __restrict__ acc,
                        const double* __restrict__ psel,
                        float* __restrict__ out)
{
    int lane = threadIdx.x;
    double v = psel[lane];
    #pragma unroll
    for (int d = 16; d; d >>= 1) v += __shfl_xor(v, d);
    double selc = __shfl(v, 0);
    double selo = __shfl(v, 32);
    if (lane == 0) {
        double N = 0.0;
        for (int b = 0; b < B_; ++b) N += acc[3 + b];
        out[0] = (float)(acc[0] / N);
        out[1] = (float)((acc[1] + selc) / N);
        out[2] = (float)((acc[2] + selo) / N);
    }
}

extern "C" void kernel_launch(void* const* d_in, const int* in_sizes, int n_in,
                              void* d_out, int out_size, void* d_ws, size_t ws_size,
                              hipStream_t stream)
{
    const float* loc     = (const float*)d_in[0];
    const float* conf    = (const float*)d_in[1];
    const float* obj     = (const float*)d_in[2];
    const float* priors  = (const float*)d_in[3];
    const float* targets = (const float*)d_in[4];
    float* out = (float*)d_out;

    char* ws = (char*)d_ws;
    double*  acc    = (double*)(ws + OFF_ACC);
    int*     nneg   = (int*)(ws + OFF_NNEG);
    int*     bp     = (int*)(ws + OFF_BP);
    float*   btovl  = (float*)(ws + OFF_BTOVL);
    int*     btidx  = (int*)(ws + OFF_BTIDX);
    float*   mine_c = (float*)(ws + OFF_MINEC);
    float*   mine_o = (float*)(ws + OFF_MINEO);
    float*   wArr   = (float*)(ws + OFF_W);
    uint8_t* posArr = (uint8_t*)(ws + OFF_POS);
    double*  pmain  = (double*)(ws + OFF_PMAIN);
    double*  psel   = (double*)(ws + OFF_PSEL);

    k_match_prior<<<dim3(P_/256, B_), 256, 0, stream>>>(priors, targets, btovl, btidx);
    k_best_prior <<<dim3(NOBJ_, B_), 256, 0, stream>>>(priors, targets, bp);
    k_scatter    <<<B_, 64, 0, stream>>>(bp, btovl, btidx);
    k_main       <<<dim3(P_/256, B_), 256, 0, stream>>>(loc, conf, obj, priors, targets,
                                                        btovl, btidx, mine_c, mine_o,
                                                        wArr, posArr, pmain);
    k_reduce     <<<1, 1024, 0, stream>>>(pmain, acc, nneg);
    k_select     <<<dim3(B_, 2), SEL_T, 0, stream>>>(mine_c, mine_o, wArr, posArr, nneg, psel);
    k_final      <<<1, 64, 0, stream>>>(acc, psel, out);
}

// Round 8
// 101.459 us; speedup vs baseline: 3.0227x; 1.2195x over previous
//
#include <hip/hip_runtime.h>
#include <cstdint>
#include <cstddef>

#define B_    32
#define P_    16384
#define C_    80
#define NOBJ_ 50
#define THRESH_ 0.5f

static constexpr size_t OFF_BP    = 1024;                        // int bp[B*NOBJ]
static constexpr size_t OFF_MINEC = 16384;
static constexpr size_t SZ_BP32   = (size_t)B_ * P_ * 4;
static constexpr size_t OFF_MINEO = OFF_MINEC + SZ_BP32;
static constexpr size_t OFF_W     = OFF_MINEO + SZ_BP32;
static constexpr size_t OFF_POS   = OFF_W + SZ_BP32;
static constexpr size_t OFF_PMAIN = OFF_POS + (size_t)B_ * P_;   // 2048*4 doubles
static constexpr size_t OFF_PSEL  = OFF_PMAIN + 2048 * 4 * 8;    // 64 doubles

__device__ __forceinline__ unsigned fkey(float f) {
    unsigned u = __float_as_uint(f);
    return (u & 0x80000000u) ? ~u : (u | 0x80000000u);
}

// Histogram add: 3 capped wave-aggregation peels (absorbs hot bins),
// then plain LDS atomicAdd fallback (diverse bins pipeline fine).
__device__ __forceinline__ void hist_add(unsigned bin, unsigned* hist) {
    int lane = threadIdx.x & 63;
    bool done = false;
    #pragma unroll
    for (int it = 0; it < 3; ++it) {
        unsigned long long active = __ballot(!done);
        if (!active) break;
        int leader = __ffsll((long long)active) - 1;
        unsigned lbin = __shfl(bin, leader);
        unsigned long long same = __ballot(!done && bin == lbin);
        if (!done && bin == lbin) {
            if (lane == leader) atomicAdd(&hist[bin], (unsigned)__popcll(same));
            done = true;
        }
    }
    if (!done) atomicAdd(&hist[bin], 1u);
}

__device__ double block_reduce_d(double v, double* sh, int nthreads) {
    int tid = threadIdx.x;
    sh[tid] = v; __syncthreads();
    for (int s = nthreads >> 1; s > 0; s >>= 1) {
        if (tid < s) sh[tid] += sh[tid + s];
        __syncthreads();
    }
    double r = sh[0]; __syncthreads();
    return r;
}

// Per-truth best prior (argmax over axis=1, first-index tie-break)
__global__ __launch_bounds__(256) void k_best_prior(
    const float* __restrict__ priors, const float* __restrict__ targets,
    int* __restrict__ bp)
{
    int t = blockIdx.x, b = blockIdx.y, tid = threadIdx.x;
    const float* tr = targets + (size_t)(b * NOBJ_ + t) * 6;
    float x1 = tr[0], y1 = tr[1], x2 = tr[2], y2 = tr[3];
    float areaA = (x2 - x1) * (y2 - y1);
    float best = -1.f; int bi = 0;
    for (int p = tid; p < P_; p += 256) {
        float4 pr = ((const float4*)priors)[p];
        float bx1 = pr.x - pr.z*0.5f, by1 = pr.y - pr.w*0.5f;
        float bx2 = pr.x + pr.z*0.5f, by2 = pr.y + pr.w*0.5f;
        float areaB = (bx2 - bx1) * (by2 - by1);
        float lx = fmaxf(x1, bx1), ly = fmaxf(y1, by1);
        float rx = fminf(x2, bx2), ry = fminf(y2, by2);
        float iw = fmaxf(rx - lx, 0.f), ih = fmaxf(ry - ly, 0.f);
        float inter = iw * ih;
        float iou = inter / (areaA + areaB - inter);
        if (iou > best) { best = iou; bi = p; }
    }
    __shared__ float sv[256];
    __shared__ int   si[256];
    sv[tid] = best; si[tid] = bi; __syncthreads();
    for (int s = 128; s > 0; s >>= 1) {
        if (tid < s) {
            if (sv[tid+s] > sv[tid] || (sv[tid+s] == sv[tid] && si[tid+s] < si[tid])) {
                sv[tid] = sv[tid+s]; si[tid] = si[tid+s];
            }
        }
        __syncthreads();
    }
    if (tid == 0) bp[b * NOBJ_ + t] = si[0];
}

// Fused main pass: per-prior match (50 IoUs) + bp last-wins override +
// encode/smoothL1/CE. Full conf logsumexp ONLY for pos rows (lse cancels
// for tgt==0: ce_c(neg) = lae - o0). Partials to pmain (no atomics).
__global__ __launch_bounds__(256) void k_main(
    const float* __restrict__ loc, const float* __restrict__ conf,
    const float* __restrict__ obj, const float* __restrict__ priors,
    const float* __restrict__ targets, const int* __restrict__ bp,
    float* __restrict__ mine_c, float* __restrict__ mine_o,
    float* __restrict__ wArr, uint8_t* __restrict__ posArr,
    double* __restrict__ pmain)
{
    int b = blockIdx.y;
    int row_base = blockIdx.x * 256;
    size_t base = (size_t)b * P_ + row_base;

    __shared__ float tg[NOBJ_ * 6];
    __shared__ float areaA[NOBJ_];
    __shared__ int   bpl[NOBJ_];
    __shared__ double wsum[4][4];
    for (int i = threadIdx.x; i < NOBJ_ * 6; i += 256) tg[i] = targets[(size_t)b * NOBJ_ * 6 + i];
    if (threadIdx.x < NOBJ_) bpl[threadIdx.x] = bp[b * NOBJ_ + threadIdx.x];
    __syncthreads();
    if (threadIdx.x < NOBJ_) {
        int t = threadIdx.x;
        areaA[t] = (tg[t*6+2] - tg[t*6+0]) * (tg[t*6+3] - tg[t*6+1]);
    }
    __syncthreads();

    int p = row_base + threadIdx.x;
    size_t ip = base + threadIdx.x;

    // ---- match: best truth for this prior (first-index tie-break) ----
    float4 prv = ((const float4*)priors)[p];
    float bx1 = prv.x - prv.z*0.5f, by1 = prv.y - prv.w*0.5f;
    float bx2 = prv.x + prv.z*0.5f, by2 = prv.y + prv.w*0.5f;
    float areaB = (bx2 - bx1) * (by2 - by1);
    float ov = -1.0f; int ti = 0;
    for (int t = 0; t < NOBJ_; ++t) {
        float lx = fmaxf(tg[t*6+0], bx1), ly = fmaxf(tg[t*6+1], by1);
        float rx = fminf(tg[t*6+2], bx2), ry = fminf(tg[t*6+3], by2);
        float iw = fmaxf(rx - lx, 0.f), ih = fmaxf(ry - ly, 0.f);
        float inter = iw * ih;
        float iou = inter / (areaA[t] + areaB - inter);
        if (iou > ov) { ov = iou; ti = t; }
    }
    // ---- scatter override (last-wins, numpy in-order semantics) ----
    for (int j = 0; j < NOBJ_; ++j) {
        if (bpl[j] == p) { ov = 2.0f; ti = j; }
    }

    float w  = tg[ti*6+5];
    bool pos = ov >= THRESH_;
    int  tgt = pos ? (int)tg[ti*6+4] : 0;

    // encode + smooth L1 (only matters for pos; cheap & coalesced)
    float tx1 = tg[ti*6+0], ty1 = tg[ti*6+1], tx2 = tg[ti*6+2], ty2 = tg[ti*6+3];
    float gx = ((tx1 + tx2) * 0.5f - prv.x) / (0.1f * prv.z);
    float gy = ((ty1 + ty2) * 0.5f - prv.y) / (0.1f * prv.w);
    float gw = __logf((tx2 - tx1) / prv.z) * 5.0f;
    float gh = __logf((ty2 - ty1) / prv.w) * 5.0f;

    float4 l4 = ((const float4*)loc)[ip];
    float sl1 = 0.f;
    {
        float lrk[4] = {l4.x, l4.y, l4.z, l4.w};
        float g[4] = {gx, gy, gw, gh};
        #pragma unroll
        for (int k = 0; k < 4; ++k) {
            float d = lrk[k] - g[k];
            float ad = fabsf(d);
            sl1 += (ad < 1.0f) ? 0.5f * d * d : ad - 0.5f;
        }
    }

    float2 ob = ((const float2*)obj)[ip];
    float o0 = ob.x, o1 = ob.y;
    float mo = fmaxf(o0, o1);
    float lae = mo + __logf(__expf(o0 - mo) + __expf(o1 - mo));

    float ce_o = lae - (pos ? o1 : o0);
    float ce_c;
    if (tgt == 0) {
        ce_c = lae - o0;                 // lse_conf cancels for background tgt
    } else {
        // pos rows only (~1-5%): full-row logsumexp, two-pass (L1-hot reread)
        const float4* cr = (const float4*)(conf + ip * C_);
        float m = -INFINITY;
        #pragma unroll 4
        for (int k = 0; k < C_/4; ++k) {
            float4 v = cr[k];
            m = fmaxf(m, fmaxf(fmaxf(v.x, v.y), fmaxf(v.z, v.w)));
        }
        float s = 0.f;
        #pragma unroll 4
        for (int k = 0; k < C_/4; ++k) {
            float4 v = cr[k];
            s += __expf(v.x - m) + __expf(v.y - m) + __expf(v.z - m) + __expf(v.w - m);
        }
        float lse = m + __logf(s);
        float ctgt = conf[ip * C_ + (tgt - 1)];
        ce_c = lse + lae - o1 - ctgt;
    }

    mine_c[ip] = pos ? 0.f : ce_c;
    mine_o[ip] = pos ? 0.f : ce_o;
    wArr[ip]   = w;
    posArr[ip] = pos ? 1 : 0;

    double v0 = pos ? (double)(sl1 * w)  : 0.0;
    double v1 = pos ? (double)(ce_c * w) : 0.0;
    double v2 = pos ? (double)(ce_o * w) : 0.0;
    double v3 = pos ? (double)w          : 0.0;

    #pragma unroll
    for (int d = 32; d; d >>= 1) {
        v0 += __shfl_xor(v0, d);
        v1 += __shfl_xor(v1, d);
        v2 += __shfl_xor(v2, d);
        v3 += __shfl_xor(v3, d);
    }
    int wid = threadIdx.x >> 6, lane = threadIdx.x & 63;
    if (lane == 0) { wsum[wid][0] = v0; wsum[wid][1] = v1; wsum[wid][2] = v2; wsum[wid][3] = v3; }
    __syncthreads();
    if (threadIdx.x == 0) {
        double t0 = 0, t1 = 0, t2 = 0, t3 = 0;
        #pragma unroll
        for (int i = 0; i < 4; ++i) { t0 += wsum[i][0]; t1 += wsum[i][1]; t2 += wsum[i][2]; t3 += wsum[i][3]; }
        size_t flat = (size_t)b * gridDim.x + blockIdx.x;
        pmain[flat*4+0] = t0; pmain[flat*4+1] = t1; pmain[flat*4+2] = t2; pmain[flat*4+3] = t3;
    }
}

#define SEL_T 1024
#define TIE_CAP 1024

// Hierarchical suffix scan: per-wave shfl_down scan + 16 wave totals.
__device__ __forceinline__ void suffix_scan_2048(unsigned* c, unsigned* wtot) {
    int tid = threadIdx.x;
    int lane = tid & 63, wid = tid >> 6;
    unsigned lo = c[2*tid], hi = c[2*tid+1];
    unsigned s_hi = hi;
    unsigned s_lo = lo + hi;
    unsigned tot = s_lo;
    unsigned run = tot;
    #pragma unroll
    for (int d = 1; d < 64; d <<= 1) {
        unsigned o = __shfl_down(run, d);
        if (lane + d < 64) run += o;
    }
    if (lane == 0) wtot[wid] = run;
    __syncthreads();
    unsigned woff = 0;
    #pragma unroll
    for (int w = 0; w < 16; ++w) if (w > wid) woff += wtot[w];
    unsigned base = woff + (run - tot);
    __syncthreads();
    c[2*tid]   = base + s_lo;
    c[2*tid+1] = base + s_hi;
    __syncthreads();
}

__device__ __forceinline__ void find_bin(unsigned* c, int K, int* s_bin, int* s_pre) {
    int tid = threadIdx.x;
    #pragma unroll
    for (int i = 0; i < 2; ++i) {
        int bb = tid + i * 1024;
        unsigned cb = c[bb];
        unsigned cn = (bb == 2047) ? 0u : c[bb + 1];
        if (cb >= (unsigned)K && cn < (unsigned)K) { *s_bin = bb; *s_pre = (int)cn; }
    }
    __syncthreads();
}

// Exact top-K selection per (batch, branch) via 3-pass radix histogram.
// Computes its own num_neg from pmain (same reduction tree as before).
__global__ __launch_bounds__(SEL_T) void k_select(
    const float* __restrict__ mine_c, const float* __restrict__ mine_o,
    const float* __restrict__ wArr, const uint8_t* __restrict__ posArr,
    const double* __restrict__ pmain, double* __restrict__ psel)
{
    int b = blockIdx.x;
    int branch = blockIdx.y;
    int tid = threadIdx.x;

    __shared__ int sK;
    if (tid < 32) {
        double pn = pmain[(size_t)(b * 64 + tid) * 4 + 3]
                  + pmain[(size_t)(b * 64 + 32 + tid) * 4 + 3];
        #pragma unroll
        for (int d = 16; d; d >>= 1) pn += __shfl_xor(pn, d);
        if (tid == 0) {
            int np = (int)pn;
            int nn = 3 * np;
            sK = nn < (P_ - 1) ? nn : (P_ - 1);
        }
    }
    __syncthreads();
    int K = sK;
    if (K <= 0) { if (tid == 0) psel[branch * B_ + b] = 0.0; return; }

    const float* mrow = (branch ? mine_o : mine_c) + (size_t)b * P_;
    const float4* m4 = (const float4*)mrow;
    const float4* w4 = (const float4*)(wArr + (size_t)b * P_);
    const uchar4* p4 = (const uchar4*)(posArr + (size_t)b * P_);

    __shared__ unsigned hist[2048];
    __shared__ unsigned wtot[16];
    __shared__ int s_bin, s_pre;
    __shared__ int tcnt;
    __shared__ int tlist[TIE_CAP];
    __shared__ double rd[SEL_T];

    // ---- pass 1: bits [31:21] ----
    hist[tid] = 0; hist[tid + 1024] = 0;
    __syncthreads();
    for (int i = tid; i < P_/4; i += SEL_T) {
        float4 v = m4[i];
        hist_add(fkey(v.x) >> 21, hist);
        hist_add(fkey(v.y) >> 21, hist);
        hist_add(fkey(v.z) >> 21, hist);
        hist_add(fkey(v.w) >> 21, hist);
    }
    __syncthreads();
    suffix_scan_2048(hist, wtot);
    find_bin(hist, K, &s_bin, &s_pre);
    int bin1 = s_bin, pre1 = s_pre;
    __syncthreads();

    // ---- pass 2: bits [20:10] ----
    hist[tid] = 0; hist[tid + 1024] = 0;
    __syncthreads();
    for (int i = tid; i < P_/4; i += SEL_T) {
        float4 v = m4[i];
        unsigned k0 = fkey(v.x), k1 = fkey(v.y), k2 = fkey(v.z), k3 = fkey(v.w);
        if ((int)(k0 >> 21) == bin1) hist_add((k0 >> 10) & 0x7FFu, hist);
        if ((int)(k1 >> 21) == bin1) hist_add((k1 >> 10) & 0x7FFu, hist);
        if ((int)(k2 >> 21) == bin1) hist_add((k2 >> 10) & 0x7FFu, hist);
        if ((int)(k3 >> 21) == bin1) hist_add((k3 >> 10) & 0x7FFu, hist);
    }
    __syncthreads();
    suffix_scan_2048(hist, wtot);
    find_bin(hist, K - pre1, &s_bin, &s_pre);
    int bin2 = s_bin, pre2 = s_pre;
    __syncthreads();

    // ---- pass 3: bits [9:0] ----
    hist[tid] = 0; hist[tid + 1024] = 0;
    __syncthreads();
    unsigned hi21 = ((unsigned)bin1 << 11) | (unsigned)bin2;
    for (int i = tid; i < P_/4; i += SEL_T) {
        float4 v = m4[i];
        unsigned k0 = fkey(v.x), k1 = fkey(v.y), k2 = fkey(v.z), k3 = fkey(v.w);
        if ((k0 >> 10) == hi21) hist_add(k0 & 0x3FFu, hist);
        if ((k1 >> 10) == hi21) hist_add(k1 & 0x3FFu, hist);
        if ((k2 >> 10) == hi21) hist_add(k2 & 0x3FFu, hist);
        if ((k3 >> 10) == hi21) hist_add(k3 & 0x3FFu, hist);
    }
    __syncthreads();
    suffix_scan_2048(hist, wtot);
    find_bin(hist, K - pre1 - pre2, &s_bin, &s_pre);
    int bin3 = s_bin, pre3 = s_pre;
    __syncthreads();

    unsigned T = (hi21 << 10) | (unsigned)bin3;
    int mslots = K - (pre1 + pre2 + pre3);

    // ---- sum k > T; gather key==T ties ----
    if (tid == 0) tcnt = 0;
    __syncthreads();
    double sum = 0.0;
    for (int i = tid; i < P_/4; i += SEL_T) {
        float4 v = m4[i];
        float4 wv = w4[i];
        uchar4 pv = p4[i];
        float  vv[4] = {v.x, v.y, v.z, v.w};
        float  ww[4] = {wv.x, wv.y, wv.z, wv.w};
        unsigned char pp[4] = {pv.x, pv.y, pv.z, pv.w};
        #pragma unroll
        for (int j = 0; j < 4; ++j) {
            unsigned k = fkey(vv[j]);
            if (k > T) {
                if (!pp[j]) sum += (double)vv[j] * (double)ww[j];
            } else if (k == T && !pp[j] && vv[j] != 0.0f) {
                int slot = atomicAdd(&tcnt, 1);
                if (slot < TIE_CAP) tlist[slot] = i * 4 + j;
            }
        }
    }
    __syncthreads();
    int n = tcnt < TIE_CAP ? tcnt : TIE_CAP;
    if (tid < n) {
        int myp = tlist[tid];
        bool sel;
        if (n <= mslots) {
            sel = true;
        } else {
            int r = 0;
            for (int j = 0; j < n; ++j) if (tlist[j] < myp) ++r;
            sel = (r < mslots);
        }
        if (sel) sum += (double)mrow[myp] * (double)(wArr + (size_t)b * P_)[myp];
    }
    double r = block_reduce_d(sum, rd, SEL_T);
    if (tid == 0) psel[branch * B_ + b] = r;
}

// Final: reduce pmain (2048x4 doubles) + psel (64) -> out[3].
__global__ __launch_bounds__(1024) void k_final(
    const double* __restrict__ pmain, const double* __restrict__ psel,
    float* __restrict__ out)
{
    int tid = threadIdx.x;
    int lane = tid & 63, wid = tid >> 6;
    double s0 = 0, s1 = 0, s2 = 0, s3 = 0;
    for (int i = tid; i < 2048; i += 1024) {
        const double* pr = pmain + (size_t)i * 4;
        s0 += pr[0]; s1 += pr[1]; s2 += pr[2]; s3 += pr[3];
    }
    #pragma unroll
    for (int d = 32; d; d >>= 1) {
        s0 += __shfl_xor(s0, d); s1 += __shfl_xor(s1, d);
        s2 += __shfl_xor(s2, d); s3 += __shfl_xor(s3, d);
    }
    __shared__ double sh[16][4];
    if (lane == 0) { sh[wid][0] = s0; sh[wid][1] = s1; sh[wid][2] = s2; sh[wid][3] = s3; }
    __syncthreads();
    if (tid == 0) {
        double a0 = 0, a1 = 0, a2 = 0, N = 0;
        #pragma unroll
        for (int i = 0; i < 16; ++i) { a0 += sh[i][0]; a1 += sh[i][1]; a2 += sh[i][2]; N += sh[i][3]; }
        double selc = 0, selo = 0;
        for (int i = 0; i < B_; ++i) { selc += psel[i]; selo += psel[B_ + i]; }
        out[0] = (float)(a0 / N);
        out[1] = (float)((a1 + selc) / N);
        out[2] = (float)((a2 + selo) / N);
    }
}

extern "C" void kernel_launch(void* const* d_in, const int* in_sizes, int n_in,
                              void* d_out, int out_size, void* d_ws, size_t ws_size,
                              hipStream_t stream)
{
    const float* loc     = (const float*)d_in[0];
    const float* conf    = (const float*)d_in[1];
    const float* obj     = (const float*)d_in[2];
    const float* priors  = (const float*)d_in[3];
    const float* targets = (const float*)d_in[4];
    float* out = (float*)d_out;

    char* ws = (char*)d_ws;
    int*     bp     = (int*)(ws + OFF_BP);
    float*   mine_c = (float*)(ws + OFF_MINEC);
    float*   mine_o = (float*)(ws + OFF_MINEO);
    float*   wArr   = (float*)(ws + OFF_W);
    uint8_t* posArr = (uint8_t*)(ws + OFF_POS);
    double*  pmain  = (double*)(ws + OFF_PMAIN);
    double*  psel   = (double*)(ws + OFF_PSEL);

    k_best_prior <<<dim3(NOBJ_, B_), 256, 0, stream>>>(priors, targets, bp);
    k_main       <<<dim3(P_/256, B_), 256, 0, stream>>>(loc, conf, obj, priors, targets,
                                                        bp, mine_c, mine_o, wArr, posArr, pmain);
    k_select     <<<dim3(B_, 2), SEL_T, 0, stream>>>(mine_c, mine_o, wArr, posArr, pmain, psel);
    k_final      <<<1, 1024, 0, stream>>>(pmain, psel, out);
}